// Round 7
// baseline (424.522 us; speedup 1.0000x reference)
//
#include <hip/hip_runtime.h>

typedef unsigned short u16;
typedef __attribute__((ext_vector_type(8))) short bf16x8;
typedef __attribute__((ext_vector_type(4))) short s16x4;
typedef __attribute__((ext_vector_type(4))) float f32x4;

__device__ __forceinline__ float bf2f(u16 u) {
  union { unsigned u; float f; } c; c.u = ((unsigned)u) << 16; return c.f;
}
__device__ __forceinline__ u16 f2bf(float f) {
  union { float f; unsigned u; } c; c.f = f;
  return (u16)((c.u + 0x7fffu + ((c.u >> 16) & 1u)) >> 16);
}
// pack two f32 -> bf16 pair (RNE). HW v_cvt_pk_bf16_f32 on gfx950 if present.
#if __has_builtin(__builtin_amdgcn_cvt_pk_bf16_f32)
__device__ __forceinline__ unsigned pkbf(float a, float b) {
  auto v = __builtin_amdgcn_cvt_pk_bf16_f32(a, b);
  return __builtin_bit_cast(unsigned, v);
}
#else
__device__ __forceinline__ unsigned pkbf(float a, float b) {
  return (unsigned)f2bf(a) | ((unsigned)f2bf(b) << 16);
}
#endif
// K=16 bf16 MFMA (B-layout == 16x16 C-layout: shuffle-free PV)
#if __has_builtin(__builtin_amdgcn_mfma_f32_16x16x16bf16_1k)
#define MFMA16(a, b, c) __builtin_amdgcn_mfma_f32_16x16x16bf16_1k(a, b, c, 0, 0, 0)
#define HAVE_MFMA16 1
#endif
// async global->LDS, 16B per lane; lptr must be wave-uniform (m104)
__device__ __forceinline__ void gl2lds16(const u16* g, u16* l) {
  __builtin_amdgcn_global_load_lds(
      (const __attribute__((address_space(1))) void*)g,
      (__attribute__((address_space(3))) void*)l, 16, 0, 0);
}

// ---------------------------------------------------------------------------
// f32 -> bf16 cast, 8 elems/thread.
// ---------------------------------------------------------------------------
__global__ __launch_bounds__(256) void cast_f32_bf16(const float* __restrict__ in,
                                                     u16* __restrict__ out, int n) {
  int i = (blockIdx.x * 256 + threadIdx.x) * 8;
  if (i >= n) return;
  float4 a = *(const float4*)&in[i];
  float4 b = *(const float4*)&in[i + 4];
  union { unsigned u[4]; bf16x8 v; } w;
  w.u[0] = pkbf(a.x, a.y); w.u[1] = pkbf(a.z, a.w);
  w.u[2] = pkbf(b.x, b.y); w.u[3] = pkbf(b.z, b.w);
  *(bf16x8*)&out[i] = w.v;
}

// ---------------------------------------------------------------------------
// f32 in [R][C] (ldin) -> bf16 out [C][R] (ldout). 64x64 tiles.
// ---------------------------------------------------------------------------
__global__ __launch_bounds__(256) void transpose_cast(const float* __restrict__ in,
                                                      u16* __restrict__ out,
                                                      int ldin, int ldout) {
  __shared__ u16 tile[64][66];
  const int tx = threadIdx.x;
  const int lr = tx & 31, lc = tx >> 5;
  const int r0 = blockIdx.y << 6, c0 = blockIdx.x << 6;
#pragma unroll
  for (int i = 0; i < 8; ++i) {
    int r = lc + (i << 3);
    float2 v = *(const float2*)&in[(size_t)(r0 + r) * ldin + c0 + (lr << 1)];
    *(unsigned*)&tile[r][lr << 1] = pkbf(v.x, v.y);
  }
  __syncthreads();
#pragma unroll
  for (int i = 0; i < 8; ++i) {
    int c = lc + (i << 3);
    unsigned v = (unsigned)tile[lr << 1][c] | ((unsigned)tile[(lr << 1) + 1][c] << 16);
    *(unsigned*)&out[(size_t)(c0 + c) * ldout + r0 + (lr << 1)] = v;
  }
}

// ---------------------------------------------------------------------------
// bf16 in [R][C] (ldin) -> bf16 out [C][R] (ldout).
// ---------------------------------------------------------------------------
__global__ __launch_bounds__(256) void transpose_bf16(const u16* __restrict__ in,
                                                      u16* __restrict__ out,
                                                      int ldin, int ldout) {
  __shared__ u16 tile[64][66];
  const int tx = threadIdx.x;
  const int lr = tx & 31, lc = tx >> 5;
  const int r0 = blockIdx.y << 6, c0 = blockIdx.x << 6;
#pragma unroll
  for (int i = 0; i < 8; ++i) {
    int r = lc + (i << 3);
    unsigned v = *(const unsigned*)&in[(size_t)(r0 + r) * ldin + c0 + (lr << 1)];
    *(unsigned*)&tile[r][lr << 1] = v;
  }
  __syncthreads();
#pragma unroll
  for (int i = 0; i < 8; ++i) {
    int c = lc + (i << 3);
    unsigned v = (unsigned)tile[lr << 1][c] | ((unsigned)tile[(lr << 1) + 1][c] << 16);
    *(unsigned*)&out[(size_t)(c0 + c) * ldout + r0 + (lr << 1)] = v;
  }
}

// ---------------------------------------------------------------------------
// m97-structure GEMM: C[M,N] = A[M,K] @ BT[N,K]^T. 128x128 tile, BK=32,
// global_load_lds 16B staging into unpadded [row][32] LDS. bf16 out.
// ---------------------------------------------------------------------------
__global__ __launch_bounds__(256) void gemm_bt(const u16* __restrict__ A,
                                               const u16* __restrict__ BT,
                                               u16* __restrict__ C,
                                               int M, int N, int K) {
  __shared__ u16 Asl[128 * 32];
  __shared__ u16 Bsl[128 * 32];
  const int tid = threadIdx.x;
  const int lane = tid & 63, wv = tid >> 6;
  const int lr = lane & 15, qd = lane >> 4;
  const int wr = wv >> 1, wc = wv & 1;
  const int m0 = blockIdx.y << 7, n0 = blockIdx.x << 7;
  const int srow = lane >> 2, scol = (lane & 3) << 3;
  const u16* Ag0 = &A[(size_t)(m0 + wv * 32 + srow) * K + scol];
  const u16* Ag1 = &A[(size_t)(m0 + wv * 32 + 16 + srow) * K + scol];
  const u16* Bg0 = &BT[(size_t)(n0 + wv * 32 + srow) * K + scol];
  const u16* Bg1 = &BT[(size_t)(n0 + wv * 32 + 16 + srow) * K + scol];
  u16* Al0 = &Asl[wv * 1024]; u16* Al1 = &Asl[wv * 1024 + 512];
  u16* Bl0 = &Bsl[wv * 1024]; u16* Bl1 = &Bsl[wv * 1024 + 512];
  f32x4 acc[4][4] = {};
  for (int k0 = 0; k0 < K; k0 += 32) {
    __syncthreads();
    gl2lds16(Ag0 + k0, Al0);
    gl2lds16(Ag1 + k0, Al1);
    gl2lds16(Bg0 + k0, Bl0);
    gl2lds16(Bg1 + k0, Bl1);
    __syncthreads();
    bf16x8 af[4], bfr[4];
#pragma unroll
    for (int i = 0; i < 4; ++i) {
      af[i]  = *(const bf16x8*)&Asl[(wr * 64 + i * 16 + lr) * 32 + qd * 8];
      bfr[i] = *(const bf16x8*)&Bsl[(wc * 64 + i * 16 + lr) * 32 + qd * 8];
    }
#pragma unroll
    for (int mi = 0; mi < 4; ++mi)
#pragma unroll
      for (int ni = 0; ni < 4; ++ni)
        acc[mi][ni] = __builtin_amdgcn_mfma_f32_16x16x32_bf16(
            af[mi], bfr[ni], acc[mi][ni], 0, 0, 0);
  }
#pragma unroll
  for (int mi = 0; mi < 4; ++mi)
#pragma unroll
    for (int ni = 0; ni < 4; ++ni)
#pragma unroll
      for (int r = 0; r < 4; ++r)
        C[(size_t)(m0 + wr * 64 + mi * 16 + qd * 4 + r) * N +
          n0 + wc * 64 + ni * 16 + lr] = f2bf(acc[mi][ni][r]);
}

// ---------------------------------------------------------------------------
// Split-K GEMM for the out-projection: C f32 += via unsafeAtomicAdd.
// Grid (N/128, M/128, splits); each split covers kspan. C must be pre-zeroed.
// Exact: float add is commutative, 2 adds/elem -> deterministic result.
// ---------------------------------------------------------------------------
__global__ __launch_bounds__(256) void gemm_bt_sk(const u16* __restrict__ A,
                                                  const u16* __restrict__ BT,
                                                  float* __restrict__ C,
                                                  int M, int N, int K, int kspan) {
  __shared__ u16 Asl[128 * 32];
  __shared__ u16 Bsl[128 * 32];
  const int tid = threadIdx.x;
  const int lane = tid & 63, wv = tid >> 6;
  const int lr = lane & 15, qd = lane >> 4;
  const int wr = wv >> 1, wc = wv & 1;
  const int m0 = blockIdx.y << 7, n0 = blockIdx.x << 7;
  const int kbeg = blockIdx.z * kspan;
  const int srow = lane >> 2, scol = (lane & 3) << 3;
  const u16* Ag0 = &A[(size_t)(m0 + wv * 32 + srow) * K + kbeg + scol];
  const u16* Ag1 = &A[(size_t)(m0 + wv * 32 + 16 + srow) * K + kbeg + scol];
  const u16* Bg0 = &BT[(size_t)(n0 + wv * 32 + srow) * K + kbeg + scol];
  const u16* Bg1 = &BT[(size_t)(n0 + wv * 32 + 16 + srow) * K + kbeg + scol];
  u16* Al0 = &Asl[wv * 1024]; u16* Al1 = &Asl[wv * 1024 + 512];
  u16* Bl0 = &Bsl[wv * 1024]; u16* Bl1 = &Bsl[wv * 1024 + 512];
  f32x4 acc[4][4] = {};
  for (int k0 = 0; k0 < kspan; k0 += 32) {
    __syncthreads();
    gl2lds16(Ag0 + k0, Al0);
    gl2lds16(Ag1 + k0, Al1);
    gl2lds16(Bg0 + k0, Bl0);
    gl2lds16(Bg1 + k0, Bl1);
    __syncthreads();
    bf16x8 af[4], bfr[4];
#pragma unroll
    for (int i = 0; i < 4; ++i) {
      af[i]  = *(const bf16x8*)&Asl[(wr * 64 + i * 16 + lr) * 32 + qd * 8];
      bfr[i] = *(const bf16x8*)&Bsl[(wc * 64 + i * 16 + lr) * 32 + qd * 8];
    }
#pragma unroll
    for (int mi = 0; mi < 4; ++mi)
#pragma unroll
      for (int ni = 0; ni < 4; ++ni)
        acc[mi][ni] = __builtin_amdgcn_mfma_f32_16x16x32_bf16(
            af[mi], bfr[ni], acc[mi][ni], 0, 0, 0);
  }
#pragma unroll
  for (int mi = 0; mi < 4; ++mi)
#pragma unroll
    for (int ni = 0; ni < 4; ++ni)
#pragma unroll
      for (int r = 0; r < 4; ++r)
        unsafeAtomicAdd(&C[(size_t)(m0 + wr * 64 + mi * 16 + qd * 4 + r) * N +
                           n0 + wc * 64 + ni * 16 + lr], acc[mi][ni][r]);
}

// ---------------------------------------------------------------------------
// Fused RMSNorm + RoPE on the fused QKV buffer [2048][6144]
// (Q cols 0..4095, K cols 4096..5119). Q scaled by 1/sqrt(128).
// ---------------------------------------------------------------------------
__global__ __launch_bounds__(256) void normrope(u16* __restrict__ QKV,
                                                const float* __restrict__ qw,
                                                const float* __restrict__ kw,
                                                const float* __restrict__ sinb,
                                                const float* __restrict__ cosb) {
  const int t = blockIdx.x;
  const int wv = threadIdx.x >> 6, l = threadIdx.x & 63;
  const float sv = sinb[t * 64 + l];
  const float cv = cosb[t * 64 + l];
  const float qscale = 0.08838834764831845f;  // 1/sqrt(128)
  u16* Q = QKV + (size_t)t * 6144;
  u16* Kb = Q + 4096;
  for (int j = wv; j < 16; j += 4) {
    u16* base = Q + j * 256;
    float x0 = bf2f(base[2 * l]);
    float x1 = bf2f(base[2 * l + 1]);
    float x2 = bf2f(base[128 + 2 * l]);
    float x3 = bf2f(base[129 + 2 * l]);
    float ss = x0 * x0 + x1 * x1 + x2 * x2 + x3 * x3;
#pragma unroll
    for (int m = 1; m < 64; m <<= 1) ss += __shfl_xor(ss, m, 64);
    float rn = rsqrtf(ss * (1.0f / 256.0f) + 1e-6f);
    float w0 = qw[2 * l], w1 = qw[2 * l + 1];
    float w2 = qw[128 + 2 * l], w3 = qw[129 + 2 * l];
    x0 *= rn * w0; x1 *= rn * w1; x2 *= rn * w2; x3 *= rn * w3;
    base[l]       = f2bf((x0 * cv - x1 * sv) * qscale);
    base[64 + l]  = f2bf((x0 * sv + x1 * cv) * qscale);
    base[128 + l] = f2bf((x2 * cv - x3 * sv) * qscale);
    base[192 + l] = f2bf((x2 * sv + x3 * cv) * qscale);
  }
  for (int j = wv; j < 8; j += 4) {
    u16* base = Kb + j * 128;
    float x0 = bf2f(base[2 * l]);
    float x1 = bf2f(base[2 * l + 1]);
    float ss = x0 * x0 + x1 * x1;
#pragma unroll
    for (int m = 1; m < 64; m <<= 1) ss += __shfl_xor(ss, m, 64);
    float rn = rsqrtf(ss * (1.0f / 128.0f) + 1e-6f);
    float w0 = kw[2 * l], w1 = kw[2 * l + 1];
    x0 *= rn * w0; x1 *= rn * w1;
    base[l]      = f2bf(x0 * cv - x1 * sv);
    base[64 + l] = f2bf(x0 * sv + x1 * cv);
  }
}

// ---------------------------------------------------------------------------
// Flash attention, S^T form, NO online max (|s|<=16 bounded), split-K=2.
// PV: softmaxed St regs feed MFMA16 B-operand directly (layout identity).
// Strides K=144 / V=80: R2/R3-measured low-conflict configuration (~half the
// conflicts of 136/72). LDS 38912 B -> 4 blocks/CU.
// ---------------------------------------------------------------------------
__global__ __launch_bounds__(256, 2) void flash(const u16* __restrict__ QKV,
                                                const u16* __restrict__ VTb,
                                                u16* __restrict__ O0,
                                                u16* __restrict__ O1,
                                                float* __restrict__ L0,
                                                float* __restrict__ L1) {
  __shared__ u16 Ksl[64 * 144];   // [key][d]
  __shared__ u16 Vsl[128 * 80];   // [d][key]
  const int tid = threadIdx.x;
  const int wv = tid >> 6, lane = tid & 63;
  const int c = lane & 15, qd = lane >> 4;
  const int h = blockIdx.y, kv = h >> 2;
  const int qb = (blockIdx.x << 7) + wv * 32;
  const int z = blockIdx.z;
  u16* Ob = z ? O1 : O0;
  float* Lb = z ? L1 : L0;
#ifndef HAVE_MFMA16
  const bool hi = lane >= 32;
  const int sl0 = ((lane >> 4) & 1) * 32 + c;
  const int sl1 = sl0 + 16;
#endif
  // Q frags (B-operand of QK): lane holds Q[q=c][d=qd*8+j]
  bf16x8 qf[2][4];
#pragma unroll
  for (int ms = 0; ms < 2; ++ms)
#pragma unroll
    for (int ks = 0; ks < 4; ++ks)
      qf[ms][ks] = *(const bf16x8*)&QKV[(size_t)(qb + ms * 16 + c) * 6144 +
                                        h * 128 + ks * 32 + qd * 8];
  f32x4 o[2][8] = {};
  float lrun[2] = {0.f, 0.f};

  const int kbeg = z << 10, kend = kbeg + 1024;
  for (int k0 = kbeg; k0 < kend; k0 += 64) {
    __syncthreads();
#pragma unroll
    for (int it = 0; it < 4; ++it) {
      int idx = tid + (it << 8);
      int key = idx >> 4, c8 = (idx & 15) << 3;
      *(bf16x8*)&Ksl[key * 144 + c8] =
          *(const bf16x8*)&QKV[(size_t)(k0 + key) * 6144 + 4096 + kv * 128 + c8];
      int d = idx >> 3, e8 = (idx & 7) << 3;
      *(bf16x8*)&Vsl[d * 80 + e8] =
          *(const bf16x8*)&VTb[(size_t)(kv * 128 + d) * 2048 + k0 + e8];
    }
    __syncthreads();
    // St[key][q]: A=K frag, B=Q frag
    f32x4 s[2][4];
#pragma unroll
    for (int ns = 0; ns < 4; ++ns) {
      f32x4 a0 = {0.f, 0.f, 0.f, 0.f}, a1 = {0.f, 0.f, 0.f, 0.f};
#pragma unroll
      for (int ks = 0; ks < 4; ++ks) {
        bf16x8 kf = *(const bf16x8*)&Ksl[(ns * 16 + c) * 144 + ks * 32 + qd * 8];
        a0 = __builtin_amdgcn_mfma_f32_16x16x32_bf16(kf, qf[0][ks], a0, 0, 0, 0);
        a1 = __builtin_amdgcn_mfma_f32_16x16x32_bf16(kf, qf[1][ks], a1, 0, 0, 0);
      }
      s[0][ns] = a0; s[1][ns] = a1;
    }
    // p = exp(s); per-lane partial row sums only
#pragma unroll
    for (int ms = 0; ms < 2; ++ms) {
      float rs = 0.f;
#pragma unroll
      for (int ns = 0; ns < 4; ++ns)
#pragma unroll
        for (int r = 0; r < 4; ++r) {
          float p = __expf(s[ms][ns][r]);
          s[ms][ns][r] = p; rs += p;
        }
      lrun[ms] += rs;
    }
#ifdef HAVE_MFMA16
    // PV: B = P straight from St regs (K=16 B-layout == C-layout), A = V^T
#pragma unroll
    for (int ns = 0; ns < 4; ++ns) {
      s16x4 pb[2];
#pragma unroll
      for (int ms = 0; ms < 2; ++ms) {
        union { unsigned u[2]; s16x4 v; } pu;
        pu.u[0] = pkbf(s[ms][ns][0], s[ms][ns][1]);
        pu.u[1] = pkbf(s[ms][ns][2], s[ms][ns][3]);
        pb[ms] = pu.v;
      }
#pragma unroll
      for (int n8 = 0; n8 < 8; ++n8) {
        s16x4 vf = *(const s16x4*)&Vsl[(n8 * 16 + c) * 80 + ns * 16 + qd * 4];
        o[0][n8] = MFMA16(vf, pb[0], o[0][n8]);
        o[1][n8] = MFMA16(vf, pb[1], o[1][n8]);
      }
    }
#else
    unsigned pk[2][4][2];
#pragma unroll
    for (int ms = 0; ms < 2; ++ms)
#pragma unroll
      for (int ns = 0; ns < 4; ++ns) {
        pk[ms][ns][0] = pkbf(s[ms][ns][0], s[ms][ns][1]);
        pk[ms][ns][1] = pkbf(s[ms][ns][2], s[ms][ns][3]);
      }
#pragma unroll
    for (int t = 0; t < 2; ++t) {
      union { int i[4]; bf16x8 v; } pb[2];
#pragma unroll
      for (int ms = 0; ms < 2; ++ms)
#pragma unroll
        for (int dw = 0; dw < 4; ++dw) {
          int rg = dw & 1;
          int sl = dw < 2 ? sl0 : sl1;
          int va = __shfl((int)pk[ms][2 * t][rg], sl, 64);
          int vb = __shfl((int)pk[ms][2 * t + 1][rg], sl, 64);
          pb[ms].i[dw] = hi ? vb : va;
        }
#pragma unroll
      for (int n8 = 0; n8 < 8; ++n8) {
        bf16x8 vf;
        *(s16x4*)&vf = *(const s16x4*)&Vsl[(n8 * 16 + c) * 80 + t * 32 + qd * 8];
        *((s16x4*)&vf + 1) = *(const s16x4*)&Vsl[(n8 * 16 + c) * 80 + t * 32 + qd * 8 + 4];
        o[0][n8] = __builtin_amdgcn_mfma_f32_16x16x32_bf16(vf, pb[0].v, o[0][n8], 0, 0, 0);
        o[1][n8] = __builtin_amdgcn_mfma_f32_16x16x32_bf16(vf, pb[1].v, o[1][n8], 0, 0, 0);
      }
    }
#endif
  }
  // reduce per-lane l partials across the 4 quads of each q-column
#pragma unroll
  for (int ms = 0; ms < 2; ++ms) {
    lrun[ms] += __shfl_xor(lrun[ms], 16, 64);
    lrun[ms] += __shfl_xor(lrun[ms], 32, 64);
  }
  if (qd == 0) {
    Lb[(qb + c) * 32 + h] = lrun[0];
    Lb[(qb + 16 + c) * 32 + h] = lrun[1];
  }
  // store unnormalized O^T: lane holds Ot[d=n8*16+qd*4+r][q=c]
#pragma unroll
  for (int ms = 0; ms < 2; ++ms)
#pragma unroll
    for (int n8 = 0; n8 < 8; ++n8) {
      union { unsigned u[2]; s16x4 v; } w;
      w.u[0] = pkbf(o[ms][n8][0], o[ms][n8][1]);
      w.u[1] = pkbf(o[ms][n8][2], o[ms][n8][3]);
      *(s16x4*)&Ob[(size_t)(qb + ms * 16 + c) * 4096 + h * 128 + n8 * 16 + qd * 4] = w.v;
    }
}

// ---------------------------------------------------------------------------
// combine: O0 <- (O0 + O1) / (L0 + L1), elementwise over [2048][32][128].
// ---------------------------------------------------------------------------
__global__ __launch_bounds__(256) void combine(u16* __restrict__ O0,
                                               const u16* __restrict__ O1,
                                               const float* __restrict__ L0,
                                               const float* __restrict__ L1) {
  int i8 = (blockIdx.x * 256 + threadIdx.x) * 8;
  int q = i8 >> 12, h = (i8 >> 7) & 31;
  float inv = 1.0f / (L0[q * 32 + h] + L1[q * 32 + h]);
  bf16x8 a = *(bf16x8*)&O0[i8];
  bf16x8 b = *(const bf16x8*)&O1[i8];
  union { unsigned u[4]; bf16x8 v; } w;
#pragma unroll
  for (int j = 0; j < 4; ++j) {
    float e0 = (bf2f((u16)a[2 * j]) + bf2f((u16)b[2 * j])) * inv;
    float e1 = (bf2f((u16)a[2 * j + 1]) + bf2f((u16)b[2 * j + 1])) * inv;
    w.u[j] = pkbf(e0, e1);
  }
  *(bf16x8*)&O0[i8] = w.v;
}

// ---------------------------------------------------------------------------
extern "C" void kernel_launch(void* const* d_in, const int* in_sizes, int n_in,
                              void* d_out, int out_size, void* d_ws, size_t ws_size,
                              hipStream_t stream) {
  const float* x    = (const float*)d_in[0];
  const float* Wq   = (const float*)d_in[1];
  const float* Wk   = (const float*)d_in[2];
  const float* Wv   = (const float*)d_in[3];
  const float* Wo   = (const float*)d_in[4];
  const float* qnw  = (const float*)d_in[5];
  const float* knw  = (const float*)d_in[6];
  const float* sinb = (const float*)d_in[7];
  const float* cosb = (const float*)d_in[8];
  float* out = (float*)d_out;
  char* ws = (char*)d_ws;
  const size_t MB = 1024 * 1024;
  // Region A 0..24 MiB: WqkvT during projections; then Op0(16) + L0/L1(0.5)
  u16* WqkvT = (u16*)(ws + 0 * MB);
  u16* Op0   = (u16*)(ws + 0 * MB);            // [2048][4096] bf16, 16 MiB
  float* L0f = (float*)(ws + 16 * MB);         // [2048][32] f32
  float* L1f = (float*)(ws + 16 * MB + 262144);
  // Region B 24..48 MiB: QKV during flash; then WoT
  u16* QKV = (u16*)(ws + 24 * MB);             // [2048][6144] bf16
  u16* WoT = (u16*)(ws + 24 * MB);             // [2048][4096] bf16 (post-flash)
  // Region C 48..64 MiB: xb during projections; then Op1
  u16* xb  = (u16*)(ws + 48 * MB);             // [2048][2048] bf16
  u16* Op1 = (u16*)(ws + 48 * MB);             // [2048][4096] bf16
  // Region D 64..68 MiB: VTb
  u16* VTb = (u16*)(ws + 64 * MB);             // [1024][2048] bf16

  cast_f32_bf16<<<2048, 256, 0, stream>>>(x, xb, 2048 * 2048);
  transpose_cast<<<dim3(64, 32), 256, 0, stream>>>(Wq, WqkvT, 4096, 2048);
  transpose_cast<<<dim3(16, 32), 256, 0, stream>>>(Wk, WqkvT + (size_t)4096 * 2048, 1024, 2048);
  transpose_cast<<<dim3(16, 32), 256, 0, stream>>>(Wv, WqkvT + (size_t)5120 * 2048, 1024, 2048);
  gemm_bt<<<dim3(48, 16), 256, 0, stream>>>(xb, WqkvT, QKV, 2048, 6144, 2048);
  normrope<<<2048, 256, 0, stream>>>(QKV, qnw, knw, sinb, cosb);
  transpose_bf16<<<dim3(16, 32), 256, 0, stream>>>(QKV + 5120, VTb, 6144, 2048);
  flash<<<dim3(16, 32, 2), 256, 0, stream>>>(QKV, VTb, Op0, Op1, L0f, L1f);
  transpose_cast<<<dim3(32, 64), 256, 0, stream>>>(Wo, WoT, 2048, 4096);
  combine<<<4096, 256, 0, stream>>>(Op0, Op1, L0f, L1f);
  hipMemsetAsync(out, 0, (size_t)2048 * 2048 * 4, stream);
  gemm_bt_sk<<<dim3(16, 16, 2), 256, 0, stream>>>(Op0, WoT, out, 2048, 2048, 4096, 2048);
  (void)in_sizes; (void)n_in; (void)out_size; (void)ws_size;
}

// Round 8
// 424.013 us; speedup vs baseline: 1.0012x; 1.0012x over previous
//
#include <hip/hip_runtime.h>

typedef unsigned short u16;
typedef __attribute__((ext_vector_type(8))) short bf16x8;
typedef __attribute__((ext_vector_type(4))) short s16x4;
typedef __attribute__((ext_vector_type(4))) float f32x4;

__device__ __forceinline__ float bf2f(u16 u) {
  union { unsigned u; float f; } c; c.u = ((unsigned)u) << 16; return c.f;
}
__device__ __forceinline__ u16 f2bf(float f) {
  union { float f; unsigned u; } c; c.f = f;
  return (u16)((c.u + 0x7fffu + ((c.u >> 16) & 1u)) >> 16);
}
// pack two f32 -> bf16 pair (RNE). HW v_cvt_pk_bf16_f32 on gfx950 if present.
#if __has_builtin(__builtin_amdgcn_cvt_pk_bf16_f32)
__device__ __forceinline__ unsigned pkbf(float a, float b) {
  auto v = __builtin_amdgcn_cvt_pk_bf16_f32(a, b);
  return __builtin_bit_cast(unsigned, v);
}
#else
__device__ __forceinline__ unsigned pkbf(float a, float b) {
  return (unsigned)f2bf(a) | ((unsigned)f2bf(b) << 16);
}
#endif
// K=16 bf16 MFMA (B-layout == 16x16 C-layout: shuffle-free PV)
#if __has_builtin(__builtin_amdgcn_mfma_f32_16x16x16bf16_1k)
#define MFMA16(a, b, c) __builtin_amdgcn_mfma_f32_16x16x16bf16_1k(a, b, c, 0, 0, 0)
#define HAVE_MFMA16 1
#endif
// async global->LDS, 16B per lane; lptr must be wave-uniform (m104)
__device__ __forceinline__ void gl2lds16(const u16* g, u16* l) {
  __builtin_amdgcn_global_load_lds(
      (const __attribute__((address_space(1))) void*)g,
      (__attribute__((address_space(3))) void*)l, 16, 0, 0);
}

// ---------------------------------------------------------------------------
// f32 -> bf16 cast, 8 elems/thread.
// ---------------------------------------------------------------------------
__global__ __launch_bounds__(256) void cast_f32_bf16(const float* __restrict__ in,
                                                     u16* __restrict__ out, int n) {
  int i = (blockIdx.x * 256 + threadIdx.x) * 8;
  if (i >= n) return;
  float4 a = *(const float4*)&in[i];
  float4 b = *(const float4*)&in[i + 4];
  union { unsigned u[4]; bf16x8 v; } w;
  w.u[0] = pkbf(a.x, a.y); w.u[1] = pkbf(a.z, a.w);
  w.u[2] = pkbf(b.x, b.y); w.u[3] = pkbf(b.z, b.w);
  *(bf16x8*)&out[i] = w.v;
}

// ---------------------------------------------------------------------------
// f32 in [R][C] (ldin) -> bf16 out [C][R] (ldout). 64x64 tiles.
// ---------------------------------------------------------------------------
__global__ __launch_bounds__(256) void transpose_cast(const float* __restrict__ in,
                                                      u16* __restrict__ out,
                                                      int ldin, int ldout) {
  __shared__ u16 tile[64][66];
  const int tx = threadIdx.x;
  const int lr = tx & 31, lc = tx >> 5;
  const int r0 = blockIdx.y << 6, c0 = blockIdx.x << 6;
#pragma unroll
  for (int i = 0; i < 8; ++i) {
    int r = lc + (i << 3);
    float2 v = *(const float2*)&in[(size_t)(r0 + r) * ldin + c0 + (lr << 1)];
    *(unsigned*)&tile[r][lr << 1] = pkbf(v.x, v.y);
  }
  __syncthreads();
#pragma unroll
  for (int i = 0; i < 8; ++i) {
    int c = lc + (i << 3);
    unsigned v = (unsigned)tile[lr << 1][c] | ((unsigned)tile[(lr << 1) + 1][c] << 16);
    *(unsigned*)&out[(size_t)(c0 + c) * ldout + r0 + (lr << 1)] = v;
  }
}

// ---------------------------------------------------------------------------
// bf16 in [R][C] (ldin) -> bf16 out [C][R] (ldout).
// ---------------------------------------------------------------------------
__global__ __launch_bounds__(256) void transpose_bf16(const u16* __restrict__ in,
                                                      u16* __restrict__ out,
                                                      int ldin, int ldout) {
  __shared__ u16 tile[64][66];
  const int tx = threadIdx.x;
  const int lr = tx & 31, lc = tx >> 5;
  const int r0 = blockIdx.y << 6, c0 = blockIdx.x << 6;
#pragma unroll
  for (int i = 0; i < 8; ++i) {
    int r = lc + (i << 3);
    unsigned v = *(const unsigned*)&in[(size_t)(r0 + r) * ldin + c0 + (lr << 1)];
    *(unsigned*)&tile[r][lr << 1] = v;
  }
  __syncthreads();
#pragma unroll
  for (int i = 0; i < 8; ++i) {
    int c = lc + (i << 3);
    unsigned v = (unsigned)tile[lr << 1][c] | ((unsigned)tile[(lr << 1) + 1][c] << 16);
    *(unsigned*)&out[(size_t)(c0 + c) * ldout + r0 + (lr << 1)] = v;
  }
}

// ---------------------------------------------------------------------------
// m97-structure GEMM: C[M,N] = A[M,K] @ BT[N,K]^T. 128x128 tile, BK=32,
// global_load_lds 16B staging into unpadded [row][32] LDS. bf16 out.
// ---------------------------------------------------------------------------
__global__ __launch_bounds__(256) void gemm_bt(const u16* __restrict__ A,
                                               const u16* __restrict__ BT,
                                               u16* __restrict__ C,
                                               int M, int N, int K) {
  __shared__ u16 Asl[128 * 32];
  __shared__ u16 Bsl[128 * 32];
  const int tid = threadIdx.x;
  const int lane = tid & 63, wv = tid >> 6;
  const int lr = lane & 15, qd = lane >> 4;
  const int wr = wv >> 1, wc = wv & 1;
  const int m0 = blockIdx.y << 7, n0 = blockIdx.x << 7;
  const int srow = lane >> 2, scol = (lane & 3) << 3;
  const u16* Ag0 = &A[(size_t)(m0 + wv * 32 + srow) * K + scol];
  const u16* Ag1 = &A[(size_t)(m0 + wv * 32 + 16 + srow) * K + scol];
  const u16* Bg0 = &BT[(size_t)(n0 + wv * 32 + srow) * K + scol];
  const u16* Bg1 = &BT[(size_t)(n0 + wv * 32 + 16 + srow) * K + scol];
  u16* Al0 = &Asl[wv * 1024]; u16* Al1 = &Asl[wv * 1024 + 512];
  u16* Bl0 = &Bsl[wv * 1024]; u16* Bl1 = &Bsl[wv * 1024 + 512];
  f32x4 acc[4][4] = {};
  for (int k0 = 0; k0 < K; k0 += 32) {
    __syncthreads();
    gl2lds16(Ag0 + k0, Al0);
    gl2lds16(Ag1 + k0, Al1);
    gl2lds16(Bg0 + k0, Bl0);
    gl2lds16(Bg1 + k0, Bl1);
    __syncthreads();
    bf16x8 af[4], bfr[4];
#pragma unroll
    for (int i = 0; i < 4; ++i) {
      af[i]  = *(const bf16x8*)&Asl[(wr * 64 + i * 16 + lr) * 32 + qd * 8];
      bfr[i] = *(const bf16x8*)&Bsl[(wc * 64 + i * 16 + lr) * 32 + qd * 8];
    }
#pragma unroll
    for (int mi = 0; mi < 4; ++mi)
#pragma unroll
      for (int ni = 0; ni < 4; ++ni)
        acc[mi][ni] = __builtin_amdgcn_mfma_f32_16x16x32_bf16(
            af[mi], bfr[ni], acc[mi][ni], 0, 0, 0);
  }
#pragma unroll
  for (int mi = 0; mi < 4; ++mi)
#pragma unroll
    for (int ni = 0; ni < 4; ++ni)
#pragma unroll
      for (int r = 0; r < 4; ++r)
        C[(size_t)(m0 + wr * 64 + mi * 16 + qd * 4 + r) * N +
          n0 + wc * 64 + ni * 16 + lr] = f2bf(acc[mi][ni][r]);
}

// ---------------------------------------------------------------------------
// Split-K GEMM for the out-projection: C f32 += via unsafeAtomicAdd.
// Grid (N/128, M/128, splits); each split covers kspan. C must be pre-zeroed.
// ---------------------------------------------------------------------------
__global__ __launch_bounds__(256) void gemm_bt_sk(const u16* __restrict__ A,
                                                  const u16* __restrict__ BT,
                                                  float* __restrict__ C,
                                                  int M, int N, int K, int kspan) {
  __shared__ u16 Asl[128 * 32];
  __shared__ u16 Bsl[128 * 32];
  const int tid = threadIdx.x;
  const int lane = tid & 63, wv = tid >> 6;
  const int lr = lane & 15, qd = lane >> 4;
  const int wr = wv >> 1, wc = wv & 1;
  const int m0 = blockIdx.y << 7, n0 = blockIdx.x << 7;
  const int kbeg = blockIdx.z * kspan;
  const int srow = lane >> 2, scol = (lane & 3) << 3;
  const u16* Ag0 = &A[(size_t)(m0 + wv * 32 + srow) * K + kbeg + scol];
  const u16* Ag1 = &A[(size_t)(m0 + wv * 32 + 16 + srow) * K + kbeg + scol];
  const u16* Bg0 = &BT[(size_t)(n0 + wv * 32 + srow) * K + kbeg + scol];
  const u16* Bg1 = &BT[(size_t)(n0 + wv * 32 + 16 + srow) * K + kbeg + scol];
  u16* Al0 = &Asl[wv * 1024]; u16* Al1 = &Asl[wv * 1024 + 512];
  u16* Bl0 = &Bsl[wv * 1024]; u16* Bl1 = &Bsl[wv * 1024 + 512];
  f32x4 acc[4][4] = {};
  for (int k0 = 0; k0 < kspan; k0 += 32) {
    __syncthreads();
    gl2lds16(Ag0 + k0, Al0);
    gl2lds16(Ag1 + k0, Al1);
    gl2lds16(Bg0 + k0, Bl0);
    gl2lds16(Bg1 + k0, Bl1);
    __syncthreads();
    bf16x8 af[4], bfr[4];
#pragma unroll
    for (int i = 0; i < 4; ++i) {
      af[i]  = *(const bf16x8*)&Asl[(wr * 64 + i * 16 + lr) * 32 + qd * 8];
      bfr[i] = *(const bf16x8*)&Bsl[(wc * 64 + i * 16 + lr) * 32 + qd * 8];
    }
#pragma unroll
    for (int mi = 0; mi < 4; ++mi)
#pragma unroll
      for (int ni = 0; ni < 4; ++ni)
        acc[mi][ni] = __builtin_amdgcn_mfma_f32_16x16x32_bf16(
            af[mi], bfr[ni], acc[mi][ni], 0, 0, 0);
  }
#pragma unroll
  for (int mi = 0; mi < 4; ++mi)
#pragma unroll
    for (int ni = 0; ni < 4; ++ni)
#pragma unroll
      for (int r = 0; r < 4; ++r)
        unsafeAtomicAdd(&C[(size_t)(m0 + wr * 64 + mi * 16 + qd * 4 + r) * N +
                           n0 + wc * 64 + ni * 16 + lr], acc[mi][ni][r]);
}

// ---------------------------------------------------------------------------
// Fused RMSNorm + RoPE on the fused QKV buffer [2048][6144]
// (Q cols 0..4095, K cols 4096..5119). Q scaled by 1/sqrt(128).
// ---------------------------------------------------------------------------
__global__ __launch_bounds__(256) void normrope(u16* __restrict__ QKV,
                                                const float* __restrict__ qw,
                                                const float* __restrict__ kw,
                                                const float* __restrict__ sinb,
                                                const float* __restrict__ cosb) {
  const int t = blockIdx.x;
  const int wv = threadIdx.x >> 6, l = threadIdx.x & 63;
  const float sv = sinb[t * 64 + l];
  const float cv = cosb[t * 64 + l];
  const float qscale = 0.08838834764831845f;  // 1/sqrt(128)
  u16* Q = QKV + (size_t)t * 6144;
  u16* Kb = Q + 4096;
  for (int j = wv; j < 16; j += 4) {
    u16* base = Q + j * 256;
    float x0 = bf2f(base[2 * l]);
    float x1 = bf2f(base[2 * l + 1]);
    float x2 = bf2f(base[128 + 2 * l]);
    float x3 = bf2f(base[129 + 2 * l]);
    float ss = x0 * x0 + x1 * x1 + x2 * x2 + x3 * x3;
#pragma unroll
    for (int m = 1; m < 64; m <<= 1) ss += __shfl_xor(ss, m, 64);
    float rn = rsqrtf(ss * (1.0f / 256.0f) + 1e-6f);
    float w0 = qw[2 * l], w1 = qw[2 * l + 1];
    float w2 = qw[128 + 2 * l], w3 = qw[129 + 2 * l];
    x0 *= rn * w0; x1 *= rn * w1; x2 *= rn * w2; x3 *= rn * w3;
    base[l]       = f2bf((x0 * cv - x1 * sv) * qscale);
    base[64 + l]  = f2bf((x0 * sv + x1 * cv) * qscale);
    base[128 + l] = f2bf((x2 * cv - x3 * sv) * qscale);
    base[192 + l] = f2bf((x2 * sv + x3 * cv) * qscale);
  }
  for (int j = wv; j < 8; j += 4) {
    u16* base = Kb + j * 128;
    float x0 = bf2f(base[2 * l]);
    float x1 = bf2f(base[2 * l + 1]);
    float ss = x0 * x0 + x1 * x1;
#pragma unroll
    for (int m = 1; m < 64; m <<= 1) ss += __shfl_xor(ss, m, 64);
    float rn = rsqrtf(ss * (1.0f / 128.0f) + 1e-6f);
    float w0 = kw[2 * l], w1 = kw[2 * l + 1];
    x0 *= rn * w0; x1 *= rn * w1;
    base[l]      = f2bf(x0 * cv - x1 * sv);
    base[64 + l] = f2bf(x0 * sv + x1 * cv);
  }
}

// ---------------------------------------------------------------------------
// Flash attention, S^T form, NO online max (|s|<=16 bounded), split-K=2.
// PV: softmaxed St regs feed MFMA16 B-operand directly (layout identity).
// Strides from bank math (bank = dword-addr mod 32):
//   K stride 144 (h=8): b128 frag reads 4-way (best under 16B-align constraint)
//   V stride 72  (h=4): b64 frag reads land 2 lanes/span -> conflict-FREE
// LDS 36864 B -> 4 blocks/CU.
// ---------------------------------------------------------------------------
__global__ __launch_bounds__(256, 2) void flash(const u16* __restrict__ QKV,
                                                const u16* __restrict__ VTb,
                                                u16* __restrict__ O0,
                                                u16* __restrict__ O1,
                                                float* __restrict__ L0,
                                                float* __restrict__ L1) {
  __shared__ u16 Ksl[64 * 144];   // [key][d]
  __shared__ u16 Vsl[128 * 72];   // [d][key]
  const int tid = threadIdx.x;
  const int wv = tid >> 6, lane = tid & 63;
  const int c = lane & 15, qd = lane >> 4;
  const int h = blockIdx.y, kv = h >> 2;
  const int qb = (blockIdx.x << 7) + wv * 32;
  const int z = blockIdx.z;
  u16* Ob = z ? O1 : O0;
  float* Lb = z ? L1 : L0;
#ifndef HAVE_MFMA16
  const bool hi = lane >= 32;
  const int sl0 = ((lane >> 4) & 1) * 32 + c;
  const int sl1 = sl0 + 16;
#endif
  // Q frags (B-operand of QK): lane holds Q[q=c][d=qd*8+j]
  bf16x8 qf[2][4];
#pragma unroll
  for (int ms = 0; ms < 2; ++ms)
#pragma unroll
    for (int ks = 0; ks < 4; ++ks)
      qf[ms][ks] = *(const bf16x8*)&QKV[(size_t)(qb + ms * 16 + c) * 6144 +
                                        h * 128 + ks * 32 + qd * 8];
  f32x4 o[2][8] = {};
  float lrun[2] = {0.f, 0.f};

  const int kbeg = z << 10, kend = kbeg + 1024;
  for (int k0 = kbeg; k0 < kend; k0 += 64) {
    __syncthreads();
#pragma unroll
    for (int it = 0; it < 4; ++it) {
      int idx = tid + (it << 8);
      int key = idx >> 4, c8 = (idx & 15) << 3;
      *(bf16x8*)&Ksl[key * 144 + c8] =
          *(const bf16x8*)&QKV[(size_t)(k0 + key) * 6144 + 4096 + kv * 128 + c8];
      int d = idx >> 3, e8 = (idx & 7) << 3;
      *(bf16x8*)&Vsl[d * 72 + e8] =
          *(const bf16x8*)&VTb[(size_t)(kv * 128 + d) * 2048 + k0 + e8];
    }
    __syncthreads();
    // St[key][q]: A=K frag, B=Q frag
    f32x4 s[2][4];
#pragma unroll
    for (int ns = 0; ns < 4; ++ns) {
      f32x4 a0 = {0.f, 0.f, 0.f, 0.f}, a1 = {0.f, 0.f, 0.f, 0.f};
#pragma unroll
      for (int ks = 0; ks < 4; ++ks) {
        bf16x8 kf = *(const bf16x8*)&Ksl[(ns * 16 + c) * 144 + ks * 32 + qd * 8];
        a0 = __builtin_amdgcn_mfma_f32_16x16x32_bf16(kf, qf[0][ks], a0, 0, 0, 0);
        a1 = __builtin_amdgcn_mfma_f32_16x16x32_bf16(kf, qf[1][ks], a1, 0, 0, 0);
      }
      s[0][ns] = a0; s[1][ns] = a1;
    }
    // p = exp(s); per-lane partial row sums only
#pragma unroll
    for (int ms = 0; ms < 2; ++ms) {
      float rs = 0.f;
#pragma unroll
      for (int ns = 0; ns < 4; ++ns)
#pragma unroll
        for (int r = 0; r < 4; ++r) {
          float p = __expf(s[ms][ns][r]);
          s[ms][ns][r] = p; rs += p;
        }
      lrun[ms] += rs;
    }
#ifdef HAVE_MFMA16
    // PV: B = P straight from St regs (K=16 B-layout == C-layout), A = V^T
#pragma unroll
    for (int ns = 0; ns < 4; ++ns) {
      s16x4 pb[2];
#pragma unroll
      for (int ms = 0; ms < 2; ++ms) {
        union { unsigned u[2]; s16x4 v; } pu;
        pu.u[0] = pkbf(s[ms][ns][0], s[ms][ns][1]);
        pu.u[1] = pkbf(s[ms][ns][2], s[ms][ns][3]);
        pb[ms] = pu.v;
      }
#pragma unroll
      for (int n8 = 0; n8 < 8; ++n8) {
        s16x4 vf = *(const s16x4*)&Vsl[(n8 * 16 + c) * 72 + ns * 16 + qd * 4];
        o[0][n8] = MFMA16(vf, pb[0], o[0][n8]);
        o[1][n8] = MFMA16(vf, pb[1], o[1][n8]);
      }
    }
#else
    unsigned pk[2][4][2];
#pragma unroll
    for (int ms = 0; ms < 2; ++ms)
#pragma unroll
      for (int ns = 0; ns < 4; ++ns) {
        pk[ms][ns][0] = pkbf(s[ms][ns][0], s[ms][ns][1]);
        pk[ms][ns][1] = pkbf(s[ms][ns][2], s[ms][ns][3]);
      }
#pragma unroll
    for (int t = 0; t < 2; ++t) {
      union { int i[4]; bf16x8 v; } pb[2];
#pragma unroll
      for (int ms = 0; ms < 2; ++ms)
#pragma unroll
        for (int dw = 0; dw < 4; ++dw) {
          int rg = dw & 1;
          int sl = dw < 2 ? sl0 : sl1;
          int va = __shfl((int)pk[ms][2 * t][rg], sl, 64);
          int vb = __shfl((int)pk[ms][2 * t + 1][rg], sl, 64);
          pb[ms].i[dw] = hi ? vb : va;
        }
#pragma unroll
      for (int n8 = 0; n8 < 8; ++n8) {
        bf16x8 vf;
        *(s16x4*)&vf = *(const s16x4*)&Vsl[(n8 * 16 + c) * 72 + t * 32 + qd * 8];
        *((s16x4*)&vf + 1) = *(const s16x4*)&Vsl[(n8 * 16 + c) * 72 + t * 32 + qd * 8 + 4];
        o[0][n8] = __builtin_amdgcn_mfma_f32_16x16x32_bf16(vf, pb[0].v, o[0][n8], 0, 0, 0);
        o[1][n8] = __builtin_amdgcn_mfma_f32_16x16x32_bf16(vf, pb[1].v, o[1][n8], 0, 0, 0);
      }
    }
#endif
  }
  // reduce per-lane l partials across the 4 quads of each q-column
#pragma unroll
  for (int ms = 0; ms < 2; ++ms) {
    lrun[ms] += __shfl_xor(lrun[ms], 16, 64);
    lrun[ms] += __shfl_xor(lrun[ms], 32, 64);
  }
  if (qd == 0) {
    Lb[(qb + c) * 32 + h] = lrun[0];
    Lb[(qb + 16 + c) * 32 + h] = lrun[1];
  }
  // store unnormalized O^T: lane holds Ot[d=n8*16+qd*4+r][q=c]
#pragma unroll
  for (int ms = 0; ms < 2; ++ms)
#pragma unroll
    for (int n8 = 0; n8 < 8; ++n8) {
      union { unsigned u[2]; s16x4 v; } w;
      w.u[0] = pkbf(o[ms][n8][0], o[ms][n8][1]);
      w.u[1] = pkbf(o[ms][n8][2], o[ms][n8][3]);
      *(s16x4*)&Ob[(size_t)(qb + ms * 16 + c) * 4096 + h * 128 + n8 * 16 + qd * 4] = w.v;
    }
}

// ---------------------------------------------------------------------------
// combine: O0 <- (O0 + O1) / (L0 + L1), elementwise over [2048][32][128].
// ---------------------------------------------------------------------------
__global__ __launch_bounds__(256) void combine(u16* __restrict__ O0,
                                               const u16* __restrict__ O1,
                                               const float* __restrict__ L0,
                                               const float* __restrict__ L1) {
  int i8 = (blockIdx.x * 256 + threadIdx.x) * 8;
  int q = i8 >> 12, h = (i8 >> 7) & 31;
  float inv = 1.0f / (L0[q * 32 + h] + L1[q * 32 + h]);
  bf16x8 a = *(bf16x8*)&O0[i8];
  bf16x8 b = *(const bf16x8*)&O1[i8];
  union { unsigned u[4]; bf16x8 v; } w;
#pragma unroll
  for (int j = 0; j < 4; ++j) {
    float e0 = (bf2f((u16)a[2 * j]) + bf2f((u16)b[2 * j])) * inv;
    float e1 = (bf2f((u16)a[2 * j + 1]) + bf2f((u16)b[2 * j + 1])) * inv;
    w.u[j] = pkbf(e0, e1);
  }
  *(bf16x8*)&O0[i8] = w.v;
}

// ---------------------------------------------------------------------------
extern "C" void kernel_launch(void* const* d_in, const int* in_sizes, int n_in,
                              void* d_out, int out_size, void* d_ws, size_t ws_size,
                              hipStream_t stream) {
  const float* x    = (const float*)d_in[0];
  const float* Wq   = (const float*)d_in[1];
  const float* Wk   = (const float*)d_in[2];
  const float* Wv   = (const float*)d_in[3];
  const float* Wo   = (const float*)d_in[4];
  const float* qnw  = (const float*)d_in[5];
  const float* knw  = (const float*)d_in[6];
  const float* sinb = (const float*)d_in[7];
  const float* cosb = (const float*)d_in[8];
  float* out = (float*)d_out;
  char* ws = (char*)d_ws;
  const size_t MB = 1024 * 1024;
  // Region A 0..24 MiB: WqkvT during projections; then Op0(16) + L0/L1(0.5)
  u16* WqkvT = (u16*)(ws + 0 * MB);
  u16* Op0   = (u16*)(ws + 0 * MB);            // [2048][4096] bf16, 16 MiB
  float* L0f = (float*)(ws + 16 * MB);         // [2048][32] f32
  float* L1f = (float*)(ws + 16 * MB + 262144);
  // Region B 24..48 MiB: QKV during flash; then WoT
  u16* QKV = (u16*)(ws + 24 * MB);             // [2048][6144] bf16
  u16* WoT = (u16*)(ws + 24 * MB);             // [2048][4096] bf16 (post-flash)
  // Region C 48..64 MiB: xb during projections; then Op1
  u16* xb  = (u16*)(ws + 48 * MB);             // [2048][2048] bf16
  u16* Op1 = (u16*)(ws + 48 * MB);             // [2048][4096] bf16
  // Region D 64..68 MiB: VTb
  u16* VTb = (u16*)(ws + 64 * MB);             // [1024][2048] bf16

  cast_f32_bf16<<<2048, 256, 0, stream>>>(x, xb, 2048 * 2048);
  transpose_cast<<<dim3(64, 32), 256, 0, stream>>>(Wq, WqkvT, 4096, 2048);
  transpose_cast<<<dim3(16, 32), 256, 0, stream>>>(Wk, WqkvT + (size_t)4096 * 2048, 1024, 2048);
  transpose_cast<<<dim3(16, 32), 256, 0, stream>>>(Wv, WqkvT + (size_t)5120 * 2048, 1024, 2048);
  gemm_bt<<<dim3(48, 16), 256, 0, stream>>>(xb, WqkvT, QKV, 2048, 6144, 2048);
  normrope<<<2048, 256, 0, stream>>>(QKV, qnw, knw, sinb, cosb);
  transpose_bf16<<<dim3(16, 32), 256, 0, stream>>>(QKV + 5120, VTb, 6144, 2048);
  flash<<<dim3(16, 32, 2), 256, 0, stream>>>(QKV, VTb, Op0, Op1, L0f, L1f);
  transpose_cast<<<dim3(32, 64), 256, 0, stream>>>(Wo, WoT, 2048, 4096);
  combine<<<4096, 256, 0, stream>>>(Op0, Op1, L0f, L1f);
  hipMemsetAsync(out, 0, (size_t)2048 * 2048 * 4, stream);
  gemm_bt_sk<<<dim3(16, 16, 4), 256, 0, stream>>>(Op0, WoT, out, 2048, 2048, 4096, 1024);
  (void)in_sizes; (void)n_in; (void)out_size; (void)ws_size;
}

// Round 9
// 400.627 us; speedup vs baseline: 1.0596x; 1.0584x over previous
//
#include <hip/hip_runtime.h>

typedef unsigned short u16;
typedef __attribute__((ext_vector_type(8))) short bf16x8;
typedef __attribute__((ext_vector_type(4))) short s16x4;
typedef __attribute__((ext_vector_type(4))) float f32x4;

__device__ __forceinline__ float bf2f(u16 u) {
  union { unsigned u; float f; } c; c.u = ((unsigned)u) << 16; return c.f;
}
__device__ __forceinline__ u16 f2bf(float f) {
  union { float f; unsigned u; } c; c.f = f;
  return (u16)((c.u + 0x7fffu + ((c.u >> 16) & 1u)) >> 16);
}
#if __has_builtin(__builtin_amdgcn_cvt_pk_bf16_f32)
__device__ __forceinline__ unsigned pkbf(float a, float b) {
  auto v = __builtin_amdgcn_cvt_pk_bf16_f32(a, b);
  return __builtin_bit_cast(unsigned, v);
}
#else
__device__ __forceinline__ unsigned pkbf(float a, float b) {
  return (unsigned)f2bf(a) | ((unsigned)f2bf(b) << 16);
}
#endif
#if __has_builtin(__builtin_amdgcn_mfma_f32_16x16x16bf16_1k)
#define MFMA16(a, b, c) __builtin_amdgcn_mfma_f32_16x16x16bf16_1k(a, b, c, 0, 0, 0)
#define HAVE_MFMA16 1
#endif
__device__ __forceinline__ void gl2lds16(const u16* g, u16* l) {
  __builtin_amdgcn_global_load_lds(
      (const __attribute__((address_space(1))) void*)g,
      (__attribute__((address_space(3))) void*)l, 16, 0, 0);
}

// ---------------------------------------------------------------------------
// transpose_cast tile body: f32 in [.][ldin] -> bf16 out [.][ldout], 64x64.
// ---------------------------------------------------------------------------
__device__ __forceinline__ void tr_cast_tile(const float* __restrict__ in,
                                             u16* __restrict__ out,
                                             int ldin, int ldout, int bx, int by) {
  __shared__ u16 tile[64][66];
  const int tx = threadIdx.x;
  const int lr = tx & 31, lc = tx >> 5;
  const int r0 = by << 6, c0 = bx << 6;
#pragma unroll
  for (int i = 0; i < 8; ++i) {
    int r = lc + (i << 3);
    float2 v = *(const float2*)&in[(size_t)(r0 + r) * ldin + c0 + (lr << 1)];
    *(unsigned*)&tile[r][lr << 1] = pkbf(v.x, v.y);
  }
  __syncthreads();
#pragma unroll
  for (int i = 0; i < 8; ++i) {
    int c = lc + (i << 3);
    unsigned v = (unsigned)tile[lr << 1][c] | ((unsigned)tile[(lr << 1) + 1][c] << 16);
    *(unsigned*)&out[(size_t)(c0 + c) * ldout + r0 + (lr << 1)] = v;
  }
}

// ---------------------------------------------------------------------------
// prep: x cast (blocks 0..2047) + WqT (2048..4095) + WkT (4096..4607) +
// WvT (4608..5119). One dispatch -> inter-op parallelism, fewer launch tails.
// ---------------------------------------------------------------------------
__global__ __launch_bounds__(256) void prep(const float* __restrict__ x,
                                            u16* __restrict__ xb,
                                            const float* __restrict__ Wq,
                                            u16* __restrict__ WqT,
                                            const float* __restrict__ Wk,
                                            u16* __restrict__ WkT,
                                            const float* __restrict__ Wv,
                                            u16* __restrict__ WvT) {
  int b = blockIdx.x;
  if (b < 2048) {
    int i = (b * 256 + threadIdx.x) * 8;
    float4 a = *(const float4*)&x[i];
    float4 c = *(const float4*)&x[i + 4];
    union { unsigned u[4]; bf16x8 v; } w;
    w.u[0] = pkbf(a.x, a.y); w.u[1] = pkbf(a.z, a.w);
    w.u[2] = pkbf(c.x, c.y); w.u[3] = pkbf(c.z, c.w);
    *(bf16x8*)&xb[i] = w.v;
  } else if (b < 4096) {
    int t = b - 2048;
    tr_cast_tile(Wq, WqT, 4096, 2048, t & 63, t >> 6);
  } else if (b < 4608) {
    int t = b - 4096;
    tr_cast_tile(Wk, WkT, 1024, 2048, t & 15, t >> 4);
  } else {
    int t = b - 4608;
    tr_cast_tile(Wv, WvT, 1024, 2048, t & 15, t >> 4);
  }
}

// ---------------------------------------------------------------------------
// Standalone Wo transpose (runs after flash; WoT reuses the QKV region).
// ---------------------------------------------------------------------------
__global__ __launch_bounds__(256) void transpose_cast(const float* __restrict__ in,
                                                      u16* __restrict__ out,
                                                      int ldin, int ldout) {
  tr_cast_tile(in, out, ldin, ldout, blockIdx.x, blockIdx.y);
}

// ---------------------------------------------------------------------------
// m97-structure GEMM: C[M,N] = A[M,K] @ BT[N,K]^T. 128x128 tile, BK=32.
// ---------------------------------------------------------------------------
__global__ __launch_bounds__(256) void gemm_bt(const u16* __restrict__ A,
                                               const u16* __restrict__ BT,
                                               u16* __restrict__ C,
                                               int M, int N, int K) {
  __shared__ u16 Asl[128 * 32];
  __shared__ u16 Bsl[128 * 32];
  const int tid = threadIdx.x;
  const int lane = tid & 63, wv = tid >> 6;
  const int lr = lane & 15, qd = lane >> 4;
  const int wr = wv >> 1, wc = wv & 1;
  const int m0 = blockIdx.y << 7, n0 = blockIdx.x << 7;
  const int srow = lane >> 2, scol = (lane & 3) << 3;
  const u16* Ag0 = &A[(size_t)(m0 + wv * 32 + srow) * K + scol];
  const u16* Ag1 = &A[(size_t)(m0 + wv * 32 + 16 + srow) * K + scol];
  const u16* Bg0 = &BT[(size_t)(n0 + wv * 32 + srow) * K + scol];
  const u16* Bg1 = &BT[(size_t)(n0 + wv * 32 + 16 + srow) * K + scol];
  u16* Al0 = &Asl[wv * 1024]; u16* Al1 = &Asl[wv * 1024 + 512];
  u16* Bl0 = &Bsl[wv * 1024]; u16* Bl1 = &Bsl[wv * 1024 + 512];
  f32x4 acc[4][4] = {};
  for (int k0 = 0; k0 < K; k0 += 32) {
    __syncthreads();
    gl2lds16(Ag0 + k0, Al0);
    gl2lds16(Ag1 + k0, Al1);
    gl2lds16(Bg0 + k0, Bl0);
    gl2lds16(Bg1 + k0, Bl1);
    __syncthreads();
    bf16x8 af[4], bfr[4];
#pragma unroll
    for (int i = 0; i < 4; ++i) {
      af[i]  = *(const bf16x8*)&Asl[(wr * 64 + i * 16 + lr) * 32 + qd * 8];
      bfr[i] = *(const bf16x8*)&Bsl[(wc * 64 + i * 16 + lr) * 32 + qd * 8];
    }
#pragma unroll
    for (int mi = 0; mi < 4; ++mi)
#pragma unroll
      for (int ni = 0; ni < 4; ++ni)
        acc[mi][ni] = __builtin_amdgcn_mfma_f32_16x16x32_bf16(
            af[mi], bfr[ni], acc[mi][ni], 0, 0, 0);
  }
#pragma unroll
  for (int mi = 0; mi < 4; ++mi)
#pragma unroll
    for (int ni = 0; ni < 4; ++ni)
#pragma unroll
      for (int r = 0; r < 4; ++r)
        C[(size_t)(m0 + wr * 64 + mi * 16 + qd * 4 + r) * N +
          n0 + wc * 64 + ni * 16 + lr] = f2bf(acc[mi][ni][r]);
}

// ---------------------------------------------------------------------------
// Split-K GEMM (out-proj): f32 += via unsafeAtomicAdd; C pre-zeroed.
// split=2 (R7/R8 A/B: split=4 doubled atomic traffic, +15us).
// ---------------------------------------------------------------------------
__global__ __launch_bounds__(256) void gemm_bt_sk(const u16* __restrict__ A,
                                                  const u16* __restrict__ BT,
                                                  float* __restrict__ C,
                                                  int M, int N, int K, int kspan) {
  __shared__ u16 Asl[128 * 32];
  __shared__ u16 Bsl[128 * 32];
  const int tid = threadIdx.x;
  const int lane = tid & 63, wv = tid >> 6;
  const int lr = lane & 15, qd = lane >> 4;
  const int wr = wv >> 1, wc = wv & 1;
  const int m0 = blockIdx.y << 7, n0 = blockIdx.x << 7;
  const int kbeg = blockIdx.z * kspan;
  const int srow = lane >> 2, scol = (lane & 3) << 3;
  const u16* Ag0 = &A[(size_t)(m0 + wv * 32 + srow) * K + kbeg + scol];
  const u16* Ag1 = &A[(size_t)(m0 + wv * 32 + 16 + srow) * K + kbeg + scol];
  const u16* Bg0 = &BT[(size_t)(n0 + wv * 32 + srow) * K + kbeg + scol];
  const u16* Bg1 = &BT[(size_t)(n0 + wv * 32 + 16 + srow) * K + kbeg + scol];
  u16* Al0 = &Asl[wv * 1024]; u16* Al1 = &Asl[wv * 1024 + 512];
  u16* Bl0 = &Bsl[wv * 1024]; u16* Bl1 = &Bsl[wv * 1024 + 512];
  f32x4 acc[4][4] = {};
  for (int k0 = 0; k0 < kspan; k0 += 32) {
    __syncthreads();
    gl2lds16(Ag0 + k0, Al0);
    gl2lds16(Ag1 + k0, Al1);
    gl2lds16(Bg0 + k0, Bl0);
    gl2lds16(Bg1 + k0, Bl1);
    __syncthreads();
    bf16x8 af[4], bfr[4];
#pragma unroll
    for (int i = 0; i < 4; ++i) {
      af[i]  = *(const bf16x8*)&Asl[(wr * 64 + i * 16 + lr) * 32 + qd * 8];
      bfr[i] = *(const bf16x8*)&Bsl[(wc * 64 + i * 16 + lr) * 32 + qd * 8];
    }
#pragma unroll
    for (int mi = 0; mi < 4; ++mi)
#pragma unroll
      for (int ni = 0; ni < 4; ++ni)
        acc[mi][ni] = __builtin_amdgcn_mfma_f32_16x16x32_bf16(
            af[mi], bfr[ni], acc[mi][ni], 0, 0, 0);
  }
#pragma unroll
  for (int mi = 0; mi < 4; ++mi)
#pragma unroll
    for (int ni = 0; ni < 4; ++ni)
#pragma unroll
      for (int r = 0; r < 4; ++r)
        unsafeAtomicAdd(&C[(size_t)(m0 + wr * 64 + mi * 16 + qd * 4 + r) * N +
                           n0 + wc * 64 + ni * 16 + lr], acc[mi][ni][r]);
}

// ---------------------------------------------------------------------------
// norm_vt: blocks 0..2047 = fused RMSNorm+RoPE on QKV [2048][6144];
// blocks 2048..2559 = V transpose (QKV cols 5120.. -> VTb [1024][2048]).
// V region is untouched by normrope -> safe in one dispatch.
// ---------------------------------------------------------------------------
__global__ __launch_bounds__(256) void norm_vt(u16* __restrict__ QKV,
                                               u16* __restrict__ VTb,
                                               const float* __restrict__ qw,
                                               const float* __restrict__ kw,
                                               const float* __restrict__ sinb,
                                               const float* __restrict__ cosb) {
  int b = blockIdx.x;
  if (b >= 2048) {
    // transpose_bf16 tile
    __shared__ u16 tile[64][66];
    int t = b - 2048;
    const int tx = threadIdx.x;
    const int lr = tx & 31, lc = tx >> 5;
    const int r0 = (t >> 4) << 6, c0 = (t & 15) << 6;
    const u16* in = QKV + 5120;
#pragma unroll
    for (int i = 0; i < 8; ++i) {
      int r = lc + (i << 3);
      unsigned v = *(const unsigned*)&in[(size_t)(r0 + r) * 6144 + c0 + (lr << 1)];
      *(unsigned*)&tile[r][lr << 1] = v;
    }
    __syncthreads();
#pragma unroll
    for (int i = 0; i < 8; ++i) {
      int c = lc + (i << 3);
      unsigned v = (unsigned)tile[lr << 1][c] | ((unsigned)tile[(lr << 1) + 1][c] << 16);
      *(unsigned*)&VTb[(size_t)(c0 + c) * 2048 + r0 + (lr << 1)] = v;
    }
    return;
  }
  const int t = b;
  const int wv = threadIdx.x >> 6, l = threadIdx.x & 63;
  const float sv = sinb[t * 64 + l];
  const float cv = cosb[t * 64 + l];
  const float qscale = 0.08838834764831845f;  // 1/sqrt(128)
  u16* Q = QKV + (size_t)t * 6144;
  u16* Kb = Q + 4096;
  for (int j = wv; j < 16; j += 4) {
    u16* base = Q + j * 256;
    float x0 = bf2f(base[2 * l]);
    float x1 = bf2f(base[2 * l + 1]);
    float x2 = bf2f(base[128 + 2 * l]);
    float x3 = bf2f(base[129 + 2 * l]);
    float ss = x0 * x0 + x1 * x1 + x2 * x2 + x3 * x3;
#pragma unroll
    for (int m = 1; m < 64; m <<= 1) ss += __shfl_xor(ss, m, 64);
    float rn = rsqrtf(ss * (1.0f / 256.0f) + 1e-6f);
    float w0 = qw[2 * l], w1 = qw[2 * l + 1];
    float w2 = qw[128 + 2 * l], w3 = qw[129 + 2 * l];
    x0 *= rn * w0; x1 *= rn * w1; x2 *= rn * w2; x3 *= rn * w3;
    base[l]       = f2bf((x0 * cv - x1 * sv) * qscale);
    base[64 + l]  = f2bf((x0 * sv + x1 * cv) * qscale);
    base[128 + l] = f2bf((x2 * cv - x3 * sv) * qscale);
    base[192 + l] = f2bf((x2 * sv + x3 * cv) * qscale);
  }
  for (int j = wv; j < 8; j += 4) {
    u16* base = Kb + j * 128;
    float x0 = bf2f(base[2 * l]);
    float x1 = bf2f(base[2 * l + 1]);
    float ss = x0 * x0 + x1 * x1;
#pragma unroll
    for (int m = 1; m < 64; m <<= 1) ss += __shfl_xor(ss, m, 64);
    float rn = rsqrtf(ss * (1.0f / 128.0f) + 1e-6f);
    float w0 = kw[2 * l], w1 = kw[2 * l + 1];
    x0 *= rn * w0; x1 *= rn * w1;
    base[l]      = f2bf(x0 * cv - x1 * sv);
    base[64 + l] = f2bf(x0 * sv + x1 * cv);
  }
}

// ---------------------------------------------------------------------------
// Flash attention, S^T form, NO online max, split-K=2, MFMA16 PV identity.
// NEW: global_load_lds staging with XOR-swizzled LDS at natural strides:
//   K[key][d]: stride 128, phys 16B-block = lblk ^ (key&7)
//   V[d][key]: stride 64,  phys 16B-block = lblk ^ (d&7)
// Verified: reader XOR cancels stager XOR; K frag reads min-phase even,
// V b64 reads 2-way (free, m136). LDS 32 KB -> 4 blocks/CU.
// ---------------------------------------------------------------------------
__global__ __launch_bounds__(256, 2) void flash(const u16* __restrict__ QKV,
                                                const u16* __restrict__ VTb,
                                                u16* __restrict__ O0,
                                                u16* __restrict__ O1,
                                                float* __restrict__ L0,
                                                float* __restrict__ L1) {
  __shared__ u16 Ksl[64 * 128];   // [key][d], swizzled
  __shared__ u16 Vsl[128 * 64];   // [d][key], swizzled
  const int tid = threadIdx.x;
  const int wv = tid >> 6, lane = tid & 63;
  const int c = lane & 15, qd = lane >> 4;
  const int h = blockIdx.y, kv = h >> 2;
  const int qb = (blockIdx.x << 7) + wv * 32;
  const int z = blockIdx.z;
  u16* Ob = z ? O1 : O0;
  float* Lb = z ? L1 : L0;
  const int cx = c & 7;  // XOR swizzle key for this lane's rows (r&7 == c&7)
  // staging lane geometry (per gl2lds16 instr: 64 lanes x 16B contiguous LDS)
  const int krow_off = lane >> 4;          // +row within 4-row K instr
  const int kpb = lane & 15;               // phys 16B block (K)
  const int vrow_off = lane >> 3;          // +row within 8-row V instr
  const int vpb = lane & 7;                // phys 16B block (V)
  // Q frags (B-operand of QK): lane holds Q[q=c][d=qd*8+j]
  bf16x8 qf[2][4];
#pragma unroll
  for (int ms = 0; ms < 2; ++ms)
#pragma unroll
    for (int ks = 0; ks < 4; ++ks)
      qf[ms][ks] = *(const bf16x8*)&QKV[(size_t)(qb + ms * 16 + c) * 6144 +
                                        h * 128 + ks * 32 + qd * 8];
  f32x4 o[2][8] = {};
  float lrun[2] = {0.f, 0.f};

  const int kbeg = z << 10, kend = kbeg + 1024;
  for (int k0 = kbeg; k0 < kend; k0 += 64) {
    __syncthreads();
#pragma unroll
    for (int it = 0; it < 4; ++it) {
      // K: instr covers rows rbase..rbase+3 (256B each)
      int rbase = (wv * 4 + it) * 4;
      int r = rbase + krow_off;
      int klb = kpb ^ (r & 7);
      gl2lds16(&QKV[(size_t)(k0 + r) * 6144 + 4096 + kv * 128 + klb * 8],
               &Ksl[rbase * 128]);
      // V: instr covers rows dbase..dbase+7 (128B each)
      int dbase = (wv * 4 + it) * 8;
      int d = dbase + vrow_off;
      int vlb = vpb ^ (d & 7);
      gl2lds16(&VTb[(size_t)(kv * 128 + d) * 2048 + k0 + vlb * 8],
               &Vsl[dbase * 64]);
    }
    __syncthreads();
    // St[key][q]: A=K frag, B=Q frag
    f32x4 s[2][4];
#pragma unroll
    for (int ns = 0; ns < 4; ++ns) {
      f32x4 a0 = {0.f, 0.f, 0.f, 0.f}, a1 = {0.f, 0.f, 0.f, 0.f};
#pragma unroll
      for (int ks = 0; ks < 4; ++ks) {
        bf16x8 kf = *(const bf16x8*)
            &Ksl[(ns * 16 + c) * 128 + (((4 * ks + qd) ^ cx) << 3)];
        a0 = __builtin_amdgcn_mfma_f32_16x16x32_bf16(kf, qf[0][ks], a0, 0, 0, 0);
        a1 = __builtin_amdgcn_mfma_f32_16x16x32_bf16(kf, qf[1][ks], a1, 0, 0, 0);
      }
      s[0][ns] = a0; s[1][ns] = a1;
    }
    // p = exp(s); per-lane partial row sums only
#pragma unroll
    for (int ms = 0; ms < 2; ++ms) {
      float rs = 0.f;
#pragma unroll
      for (int ns = 0; ns < 4; ++ns)
#pragma unroll
        for (int r = 0; r < 4; ++r) {
          float p = __expf(s[ms][ns][r]);
          s[ms][ns][r] = p; rs += p;
        }
      lrun[ms] += rs;
    }
#ifdef HAVE_MFMA16
    // PV: B = P straight from St regs (K=16 B-layout == C-layout), A = V^T
#pragma unroll
    for (int ns = 0; ns < 4; ++ns) {
      s16x4 pb[2];
#pragma unroll
      for (int ms = 0; ms < 2; ++ms) {
        union { unsigned u[2]; s16x4 v; } pu;
        pu.u[0] = pkbf(s[ms][ns][0], s[ms][ns][1]);
        pu.u[1] = pkbf(s[ms][ns][2], s[ms][ns][3]);
        pb[ms] = pu.v;
      }
      const int voff = ((((2 * ns) + (qd >> 1)) ^ cx) << 3) + (qd & 1) * 4;
#pragma unroll
      for (int n8 = 0; n8 < 8; ++n8) {
        s16x4 vf = *(const s16x4*)&Vsl[(n8 * 16 + c) * 64 + voff];
        o[0][n8] = MFMA16(vf, pb[0], o[0][n8]);
        o[1][n8] = MFMA16(vf, pb[1], o[1][n8]);
      }
    }
#else
    unsigned pk[2][4][2];
#pragma unroll
    for (int ms = 0; ms < 2; ++ms)
#pragma unroll
      for (int ns = 0; ns < 4; ++ns) {
        pk[ms][ns][0] = pkbf(s[ms][ns][0], s[ms][ns][1]);
        pk[ms][ns][1] = pkbf(s[ms][ns][2], s[ms][ns][3]);
      }
    const bool hi = lane >= 32;
    const int sl0 = ((lane >> 4) & 1) * 32 + c;
    const int sl1 = sl0 + 16;
#pragma unroll
    for (int t2 = 0; t2 < 2; ++t2) {
      union { int i[4]; bf16x8 v; } pb[2];
#pragma unroll
      for (int ms = 0; ms < 2; ++ms)
#pragma unroll
        for (int dw = 0; dw < 4; ++dw) {
          int rg = dw & 1;
          int sl = dw < 2 ? sl0 : sl1;
          int va = __shfl((int)pk[ms][2 * t2][rg], sl, 64);
          int vb = __shfl((int)pk[ms][2 * t2 + 1][rg], sl, 64);
          pb[ms].i[dw] = hi ? vb : va;
        }
#pragma unroll
      for (int n8 = 0; n8 < 8; ++n8) {
        bf16x8 vf = *(const bf16x8*)
            &Vsl[(n8 * 16 + c) * 64 + (((4 * t2 + qd) ^ cx) << 3)];
        o[0][n8] = __builtin_amdgcn_mfma_f32_16x16x32_bf16(vf, pb[0].v, o[0][n8], 0, 0, 0);
        o[1][n8] = __builtin_amdgcn_mfma_f32_16x16x32_bf16(vf, pb[1].v, o[1][n8], 0, 0, 0);
      }
    }
#endif
  }
  // reduce per-lane l partials across the 4 quads of each q-column
#pragma unroll
  for (int ms = 0; ms < 2; ++ms) {
    lrun[ms] += __shfl_xor(lrun[ms], 16, 64);
    lrun[ms] += __shfl_xor(lrun[ms], 32, 64);
  }
  if (qd == 0) {
    Lb[(qb + c) * 32 + h] = lrun[0];
    Lb[(qb + 16 + c) * 32 + h] = lrun[1];
  }
  // store unnormalized O^T: lane holds Ot[d=n8*16+qd*4+r][q=c]
#pragma unroll
  for (int ms = 0; ms < 2; ++ms)
#pragma unroll
    for (int n8 = 0; n8 < 8; ++n8) {
      union { unsigned u[2]; s16x4 v; } w;
      w.u[0] = pkbf(o[ms][n8][0], o[ms][n8][1]);
      w.u[1] = pkbf(o[ms][n8][2], o[ms][n8][3]);
      *(s16x4*)&Ob[(size_t)(qb + ms * 16 + c) * 4096 + h * 128 + n8 * 16 + qd * 4] = w.v;
    }
}

// ---------------------------------------------------------------------------
// combine: O0 <- (O0 + O1) / (L0 + L1), elementwise over [2048][32][128].
// ---------------------------------------------------------------------------
__global__ __launch_bounds__(256) void combine(u16* __restrict__ O0,
                                               const u16* __restrict__ O1,
                                               const float* __restrict__ L0,
                                               const float* __restrict__ L1) {
  int i8 = (blockIdx.x * 256 + threadIdx.x) * 8;
  int q = i8 >> 12, h = (i8 >> 7) & 31;
  float inv = 1.0f / (L0[q * 32 + h] + L1[q * 32 + h]);
  bf16x8 a = *(bf16x8*)&O0[i8];
  bf16x8 b = *(const bf16x8*)&O1[i8];
  union { unsigned u[4]; bf16x8 v; } w;
#pragma unroll
  for (int j = 0; j < 4; ++j) {
    float e0 = (bf2f((u16)a[2 * j]) + bf2f((u16)b[2 * j])) * inv;
    float e1 = (bf2f((u16)a[2 * j + 1]) + bf2f((u16)b[2 * j + 1])) * inv;
    w.u[j] = pkbf(e0, e1);
  }
  *(bf16x8*)&O0[i8] = w.v;
}

// ---------------------------------------------------------------------------
extern "C" void kernel_launch(void* const* d_in, const int* in_sizes, int n_in,
                              void* d_out, int out_size, void* d_ws, size_t ws_size,
                              hipStream_t stream) {
  const float* x    = (const float*)d_in[0];
  const float* Wq   = (const float*)d_in[1];
  const float* Wk   = (const float*)d_in[2];
  const float* Wv   = (const float*)d_in[3];
  const float* Wo   = (const float*)d_in[4];
  const float* qnw  = (const float*)d_in[5];
  const float* knw  = (const float*)d_in[6];
  const float* sinb = (const float*)d_in[7];
  const float* cosb = (const float*)d_in[8];
  float* out = (float*)d_out;
  char* ws = (char*)d_ws;
  const size_t MB = 1024 * 1024;
  // Region A 0..24 MiB: WqkvT during projections; then Op0(16) + L0/L1(0.5)
  u16* WqkvT = (u16*)(ws + 0 * MB);
  u16* Op0   = (u16*)(ws + 0 * MB);            // [2048][4096] bf16
  float* L0f = (float*)(ws + 16 * MB);
  float* L1f = (float*)(ws + 16 * MB + 262144);
  // Region B 24..48 MiB: QKV during flash; then WoT
  u16* QKV = (u16*)(ws + 24 * MB);             // [2048][6144] bf16
  u16* WoT = (u16*)(ws + 24 * MB);             // [2048][4096] bf16 (post-flash)
  // Region C 48..64 MiB: xb during projections; then Op1
  u16* xb  = (u16*)(ws + 48 * MB);             // [2048][2048] bf16
  u16* Op1 = (u16*)(ws + 48 * MB);             // [2048][4096] bf16
  // Region D 64..68 MiB: VTb
  u16* VTb = (u16*)(ws + 64 * MB);             // [1024][2048] bf16

  prep<<<5120, 256, 0, stream>>>(x, xb, Wq, WqkvT,
                                 Wk, WqkvT + (size_t)4096 * 2048,
                                 Wv, WqkvT + (size_t)5120 * 2048);
  gemm_bt<<<dim3(48, 16), 256, 0, stream>>>(xb, WqkvT, QKV, 2048, 6144, 2048);
  norm_vt<<<2560, 256, 0, stream>>>(QKV, VTb, qnw, knw, sinb, cosb);
  flash<<<dim3(16, 32, 2), 256, 0, stream>>>(QKV, VTb, Op0, Op1, L0f, L1f);
  transpose_cast<<<dim3(32, 64), 256, 0, stream>>>(Wo, WoT, 2048, 4096);
  combine<<<4096, 256, 0, stream>>>(Op0, Op1, L0f, L1f);
  hipMemsetAsync(out, 0, (size_t)2048 * 2048 * 4, stream);
  gemm_bt_sk<<<dim3(16, 16, 2), 256, 0, stream>>>(Op0, WoT, out, 2048, 2048, 4096, 2048);
  (void)in_sizes; (void)n_in; (void)out_size; (void)ws_size;
}

// Round 10
// 377.625 us; speedup vs baseline: 1.1242x; 1.0609x over previous
//
#include <hip/hip_runtime.h>

typedef unsigned short u16;
typedef __attribute__((ext_vector_type(8))) short bf16x8;
typedef __attribute__((ext_vector_type(4))) short s16x4;
typedef __attribute__((ext_vector_type(4))) float f32x4;

__device__ __forceinline__ float bf2f(u16 u) {
  union { unsigned u; float f; } c; c.u = ((unsigned)u) << 16; return c.f;
}
__device__ __forceinline__ u16 f2bf(float f) {
  union { float f; unsigned u; } c; c.f = f;
  return (u16)((c.u + 0x7fffu + ((c.u >> 16) & 1u)) >> 16);
}
#if __has_builtin(__builtin_amdgcn_cvt_pk_bf16_f32)
__device__ __forceinline__ unsigned pkbf(float a, float b) {
  auto v = __builtin_amdgcn_cvt_pk_bf16_f32(a, b);
  return __builtin_bit_cast(unsigned, v);
}
#else
__device__ __forceinline__ unsigned pkbf(float a, float b) {
  return (unsigned)f2bf(a) | ((unsigned)f2bf(b) << 16);
}
#endif
#if __has_builtin(__builtin_amdgcn_mfma_f32_16x16x16bf16_1k)
#define MFMA16(a, b, c) __builtin_amdgcn_mfma_f32_16x16x16bf16_1k(a, b, c, 0, 0, 0)
#define HAVE_MFMA16 1
#endif
// raw exp2 (v_exp_f32); Q pre-scaled by log2e/sqrt(128) so p = e^(qk/sqrt128)
#if __has_builtin(__builtin_amdgcn_exp2f)
#define EXP2(x) __builtin_amdgcn_exp2f(x)
#else
#define EXP2(x) __expf((x) * 0.69314718f)
#endif
__device__ __forceinline__ void gl2lds16(const u16* g, u16* l) {
  __builtin_amdgcn_global_load_lds(
      (const __attribute__((address_space(1))) void*)g,
      (__attribute__((address_space(3))) void*)l, 16, 0, 0);
}

// ---------------------------------------------------------------------------
// transpose_cast tile body: f32 in [.][ldin] -> bf16 out [.][ldout], 64x64.
// ---------------------------------------------------------------------------
__device__ __forceinline__ void tr_cast_tile(const float* __restrict__ in,
                                             u16* __restrict__ out,
                                             int ldin, int ldout, int bx, int by) {
  __shared__ u16 tile[64][66];
  const int tx = threadIdx.x;
  const int lr = tx & 31, lc = tx >> 5;
  const int r0 = by << 6, c0 = bx << 6;
#pragma unroll
  for (int i = 0; i < 8; ++i) {
    int r = lc + (i << 3);
    float2 v = *(const float2*)&in[(size_t)(r0 + r) * ldin + c0 + (lr << 1)];
    *(unsigned*)&tile[r][lr << 1] = pkbf(v.x, v.y);
  }
  __syncthreads();
#pragma unroll
  for (int i = 0; i < 8; ++i) {
    int c = lc + (i << 3);
    unsigned v = (unsigned)tile[lr << 1][c] | ((unsigned)tile[(lr << 1) + 1][c] << 16);
    *(unsigned*)&out[(size_t)(c0 + c) * ldout + r0 + (lr << 1)] = v;
  }
}

// ---------------------------------------------------------------------------
// prep: x cast (blocks 0..2047) + WqT (2048..4095) + WkT (4096..4607) +
// WvT (4608..5119).
// ---------------------------------------------------------------------------
__global__ __launch_bounds__(256) void prep(const float* __restrict__ x,
                                            u16* __restrict__ xb,
                                            const float* __restrict__ Wq,
                                            u16* __restrict__ WqT,
                                            const float* __restrict__ Wk,
                                            u16* __restrict__ WkT,
                                            const float* __restrict__ Wv,
                                            u16* __restrict__ WvT) {
  int b = blockIdx.x;
  if (b < 2048) {
    int i = (b * 256 + threadIdx.x) * 8;
    float4 a = *(const float4*)&x[i];
    float4 c = *(const float4*)&x[i + 4];
    union { unsigned u[4]; bf16x8 v; } w;
    w.u[0] = pkbf(a.x, a.y); w.u[1] = pkbf(a.z, a.w);
    w.u[2] = pkbf(c.x, c.y); w.u[3] = pkbf(c.z, c.w);
    *(bf16x8*)&xb[i] = w.v;
  } else if (b < 4096) {
    int t = b - 2048;
    tr_cast_tile(Wq, WqT, 4096, 2048, t & 63, t >> 6);
  } else if (b < 4608) {
    int t = b - 4096;
    tr_cast_tile(Wk, WkT, 1024, 2048, t & 15, t >> 4);
  } else {
    int t = b - 4608;
    tr_cast_tile(Wv, WvT, 1024, 2048, t & 15, t >> 4);
  }
}

__global__ __launch_bounds__(256) void transpose_cast(const float* __restrict__ in,
                                                      u16* __restrict__ out,
                                                      int ldin, int ldout) {
  tr_cast_tile(in, out, ldin, ldout, blockIdx.x, blockIdx.y);
}

// ---------------------------------------------------------------------------
// BK=64 GEMM: C[M,N] = A[M,K] @ BT[N,K]^T. 128x128 tile, two [128][32]
// panels per operand (each panel = verified m97 LDS pattern), 32 MFMA per
// barrier pair (halved barrier drains vs BK=32). bf16 out.
// ---------------------------------------------------------------------------
__global__ __launch_bounds__(256) void gemm_bt(const u16* __restrict__ A,
                                               const u16* __restrict__ BT,
                                               u16* __restrict__ C,
                                               int M, int N, int K) {
  __shared__ u16 Asl[2][128 * 32];
  __shared__ u16 Bsl[2][128 * 32];
  const int tid = threadIdx.x;
  const int lane = tid & 63, wv = tid >> 6;
  const int lr = lane & 15, qd = lane >> 4;
  const int wr = wv >> 1, wc = wv & 1;
  const int m0 = blockIdx.y << 7, n0 = blockIdx.x << 7;
  const int srow = lane >> 2, scol = (lane & 3) << 3;
  const u16* Ag = &A[(size_t)(m0 + wv * 32 + srow) * K + scol];
  const u16* Bg = &BT[(size_t)(n0 + wv * 32 + srow) * K + scol];
  const size_t rstr16 = (size_t)16 * K;
  f32x4 acc[4][4] = {};
  for (int k0 = 0; k0 < K; k0 += 64) {
    __syncthreads();
#pragma unroll
    for (int p = 0; p < 2; ++p) {
#pragma unroll
      for (int hh = 0; hh < 2; ++hh) {
        gl2lds16(Ag + k0 + p * 32 + hh * rstr16, &Asl[p][wv * 1024 + hh * 512]);
        gl2lds16(Bg + k0 + p * 32 + hh * rstr16, &Bsl[p][wv * 1024 + hh * 512]);
      }
    }
    __syncthreads();
#pragma unroll
    for (int p = 0; p < 2; ++p) {
      bf16x8 af[4], bfr[4];
#pragma unroll
      for (int i = 0; i < 4; ++i) {
        af[i]  = *(const bf16x8*)&Asl[p][(wr * 64 + i * 16 + lr) * 32 + qd * 8];
        bfr[i] = *(const bf16x8*)&Bsl[p][(wc * 64 + i * 16 + lr) * 32 + qd * 8];
      }
#pragma unroll
      for (int mi = 0; mi < 4; ++mi)
#pragma unroll
        for (int ni = 0; ni < 4; ++ni)
          acc[mi][ni] = __builtin_amdgcn_mfma_f32_16x16x32_bf16(
              af[mi], bfr[ni], acc[mi][ni], 0, 0, 0);
    }
  }
#pragma unroll
  for (int mi = 0; mi < 4; ++mi)
#pragma unroll
    for (int ni = 0; ni < 4; ++ni)
#pragma unroll
      for (int r = 0; r < 4; ++r)
        C[(size_t)(m0 + wr * 64 + mi * 16 + qd * 4 + r) * N +
          n0 + wc * 64 + ni * 16 + lr] = f2bf(acc[mi][ni][r]);
}

// ---------------------------------------------------------------------------
// BK=64 split-K GEMM (out-proj): f32 += via unsafeAtomicAdd; C pre-zeroed.
// ---------------------------------------------------------------------------
__global__ __launch_bounds__(256) void gemm_bt_sk(const u16* __restrict__ A,
                                                  const u16* __restrict__ BT,
                                                  float* __restrict__ C,
                                                  int M, int N, int K, int kspan) {
  __shared__ u16 Asl[2][128 * 32];
  __shared__ u16 Bsl[2][128 * 32];
  const int tid = threadIdx.x;
  const int lane = tid & 63, wv = tid >> 6;
  const int lr = lane & 15, qd = lane >> 4;
  const int wr = wv >> 1, wc = wv & 1;
  const int m0 = blockIdx.y << 7, n0 = blockIdx.x << 7;
  const int kbeg = blockIdx.z * kspan;
  const int srow = lane >> 2, scol = (lane & 3) << 3;
  const u16* Ag = &A[(size_t)(m0 + wv * 32 + srow) * K + kbeg + scol];
  const u16* Bg = &BT[(size_t)(n0 + wv * 32 + srow) * K + kbeg + scol];
  const size_t rstr16 = (size_t)16 * K;
  f32x4 acc[4][4] = {};
  for (int k0 = 0; k0 < kspan; k0 += 64) {
    __syncthreads();
#pragma unroll
    for (int p = 0; p < 2; ++p) {
#pragma unroll
      for (int hh = 0; hh < 2; ++hh) {
        gl2lds16(Ag + k0 + p * 32 + hh * rstr16, &Asl[p][wv * 1024 + hh * 512]);
        gl2lds16(Bg + k0 + p * 32 + hh * rstr16, &Bsl[p][wv * 1024 + hh * 512]);
      }
    }
    __syncthreads();
#pragma unroll
    for (int p = 0; p < 2; ++p) {
      bf16x8 af[4], bfr[4];
#pragma unroll
      for (int i = 0; i < 4; ++i) {
        af[i]  = *(const bf16x8*)&Asl[p][(wr * 64 + i * 16 + lr) * 32 + qd * 8];
        bfr[i] = *(const bf16x8*)&Bsl[p][(wc * 64 + i * 16 + lr) * 32 + qd * 8];
      }
#pragma unroll
      for (int mi = 0; mi < 4; ++mi)
#pragma unroll
        for (int ni = 0; ni < 4; ++ni)
          acc[mi][ni] = __builtin_amdgcn_mfma_f32_16x16x32_bf16(
              af[mi], bfr[ni], acc[mi][ni], 0, 0, 0);
    }
  }
#pragma unroll
  for (int mi = 0; mi < 4; ++mi)
#pragma unroll
    for (int ni = 0; ni < 4; ++ni)
#pragma unroll
      for (int r = 0; r < 4; ++r)
        unsafeAtomicAdd(&C[(size_t)(m0 + wr * 64 + mi * 16 + qd * 4 + r) * N +
                           n0 + wc * 64 + ni * 16 + lr], acc[mi][ni][r]);
}

// ---------------------------------------------------------------------------
// norm_vt: blocks 0..2047 = fused RMSNorm+RoPE on QKV [2048][6144];
// blocks 2048..2559 = V transpose. Q scaled by log2e/sqrt(128) (exp2 fold).
// ---------------------------------------------------------------------------
__global__ __launch_bounds__(256) void norm_vt(u16* __restrict__ QKV,
                                               u16* __restrict__ VTb,
                                               const float* __restrict__ qw,
                                               const float* __restrict__ kw,
                                               const float* __restrict__ sinb,
                                               const float* __restrict__ cosb) {
  int b = blockIdx.x;
  if (b >= 2048) {
    __shared__ u16 tile[64][66];
    int t = b - 2048;
    const int tx = threadIdx.x;
    const int lr = tx & 31, lc = tx >> 5;
    const int r0 = (t >> 4) << 6, c0 = (t & 15) << 6;
    const u16* in = QKV + 5120;
#pragma unroll
    for (int i = 0; i < 8; ++i) {
      int r = lc + (i << 3);
      unsigned v = *(const unsigned*)&in[(size_t)(r0 + r) * 6144 + c0 + (lr << 1)];
      *(unsigned*)&tile[r][lr << 1] = v;
    }
    __syncthreads();
#pragma unroll
    for (int i = 0; i < 8; ++i) {
      int c = lc + (i << 3);
      unsigned v = (unsigned)tile[lr << 1][c] | ((unsigned)tile[(lr << 1) + 1][c] << 16);
      *(unsigned*)&VTb[(size_t)(c0 + c) * 2048 + r0 + (lr << 1)] = v;
    }
    return;
  }
  const int t = b;
  const int wv = threadIdx.x >> 6, l = threadIdx.x & 63;
  const float sv = sinb[t * 64 + l];
  const float cv = cosb[t * 64 + l];
  const float qscale = 0.12753102543f;  // log2(e)/sqrt(128)
  u16* Q = QKV + (size_t)t * 6144;
  u16* Kb = Q + 4096;
  for (int j = wv; j < 16; j += 4) {
    u16* base = Q + j * 256;
    float x0 = bf2f(base[2 * l]);
    float x1 = bf2f(base[2 * l + 1]);
    float x2 = bf2f(base[128 + 2 * l]);
    float x3 = bf2f(base[129 + 2 * l]);
    float ss = x0 * x0 + x1 * x1 + x2 * x2 + x3 * x3;
#pragma unroll
    for (int m = 1; m < 64; m <<= 1) ss += __shfl_xor(ss, m, 64);
    float rn = rsqrtf(ss * (1.0f / 256.0f) + 1e-6f);
    float w0 = qw[2 * l], w1 = qw[2 * l + 1];
    float w2 = qw[128 + 2 * l], w3 = qw[129 + 2 * l];
    x0 *= rn * w0; x1 *= rn * w1; x2 *= rn * w2; x3 *= rn * w3;
    base[l]       = f2bf((x0 * cv - x1 * sv) * qscale);
    base[64 + l]  = f2bf((x0 * sv + x1 * cv) * qscale);
    base[128 + l] = f2bf((x2 * cv - x3 * sv) * qscale);
    base[192 + l] = f2bf((x2 * sv + x3 * cv) * qscale);
  }
  for (int j = wv; j < 8; j += 4) {
    u16* base = Kb + j * 128;
    float x0 = bf2f(base[2 * l]);
    float x1 = bf2f(base[2 * l + 1]);
    float ss = x0 * x0 + x1 * x1;
#pragma unroll
    for (int m = 1; m < 64; m <<= 1) ss += __shfl_xor(ss, m, 64);
    float rn = rsqrtf(ss * (1.0f / 128.0f) + 1e-6f);
    float w0 = kw[2 * l], w1 = kw[2 * l + 1];
    x0 *= rn * w0; x1 *= rn * w1;
    base[l]      = f2bf(x0 * cv - x1 * sv);
    base[64 + l] = f2bf(x0 * sv + x1 * cv);
  }
}

// ---------------------------------------------------------------------------
// Flash attention, S^T form, NO online max, split-K=2, MFMA16 PV identity,
// global_load_lds staging with XOR-swizzled LDS (R9 structure), p=exp2(s).
// ---------------------------------------------------------------------------
__global__ __launch_bounds__(256, 2) void flash(const u16* __restrict__ QKV,
                                                const u16* __restrict__ VTb,
                                                u16* __restrict__ O0,
                                                u16* __restrict__ O1,
                                                float* __restrict__ L0,
                                                float* __restrict__ L1) {
  __shared__ u16 Ksl[64 * 128];   // [key][d], swizzled
  __shared__ u16 Vsl[128 * 64];   // [d][key], swizzled
  const int tid = threadIdx.x;
  const int wv = tid >> 6, lane = tid & 63;
  const int c = lane & 15, qd = lane >> 4;
  const int h = blockIdx.y, kv = h >> 2;
  const int qb = (blockIdx.x << 7) + wv * 32;
  const int z = blockIdx.z;
  u16* Ob = z ? O1 : O0;
  float* Lb = z ? L1 : L0;
  const int cx = c & 7;
  const int krow_off = lane >> 4;
  const int kpb = lane & 15;
  const int vrow_off = lane >> 3;
  const int vpb = lane & 7;
  bf16x8 qf[2][4];
#pragma unroll
  for (int ms = 0; ms < 2; ++ms)
#pragma unroll
    for (int ks = 0; ks < 4; ++ks)
      qf[ms][ks] = *(const bf16x8*)&QKV[(size_t)(qb + ms * 16 + c) * 6144 +
                                        h * 128 + ks * 32 + qd * 8];
  f32x4 o[2][8] = {};
  float lrun[2] = {0.f, 0.f};

  const int kbeg = z << 10, kend = kbeg + 1024;
  for (int k0 = kbeg; k0 < kend; k0 += 64) {
    __syncthreads();
#pragma unroll
    for (int it = 0; it < 4; ++it) {
      int rbase = (wv * 4 + it) * 4;
      int r = rbase + krow_off;
      int klb = kpb ^ (r & 7);
      gl2lds16(&QKV[(size_t)(k0 + r) * 6144 + 4096 + kv * 128 + klb * 8],
               &Ksl[rbase * 128]);
      int dbase = (wv * 4 + it) * 8;
      int d = dbase + vrow_off;
      int vlb = vpb ^ (d & 7);
      gl2lds16(&VTb[(size_t)(kv * 128 + d) * 2048 + k0 + vlb * 8],
               &Vsl[dbase * 64]);
    }
    __syncthreads();
    f32x4 s[2][4];
#pragma unroll
    for (int ns = 0; ns < 4; ++ns) {
      f32x4 a0 = {0.f, 0.f, 0.f, 0.f}, a1 = {0.f, 0.f, 0.f, 0.f};
#pragma unroll
      for (int ks = 0; ks < 4; ++ks) {
        bf16x8 kf = *(const bf16x8*)
            &Ksl[(ns * 16 + c) * 128 + (((4 * ks + qd) ^ cx) << 3)];
        a0 = __builtin_amdgcn_mfma_f32_16x16x32_bf16(kf, qf[0][ks], a0, 0, 0, 0);
        a1 = __builtin_amdgcn_mfma_f32_16x16x32_bf16(kf, qf[1][ks], a1, 0, 0, 0);
      }
      s[0][ns] = a0; s[1][ns] = a1;
    }
#pragma unroll
    for (int ms = 0; ms < 2; ++ms) {
      float rs = 0.f;
#pragma unroll
      for (int ns = 0; ns < 4; ++ns)
#pragma unroll
        for (int r = 0; r < 4; ++r) {
          float p = EXP2(s[ms][ns][r]);
          s[ms][ns][r] = p; rs += p;
        }
      lrun[ms] += rs;
    }
#ifdef HAVE_MFMA16
#pragma unroll
    for (int ns = 0; ns < 4; ++ns) {
      s16x4 pb[2];
#pragma unroll
      for (int ms = 0; ms < 2; ++ms) {
        union { unsigned u[2]; s16x4 v; } pu;
        pu.u[0] = pkbf(s[ms][ns][0], s[ms][ns][1]);
        pu.u[1] = pkbf(s[ms][ns][2], s[ms][ns][3]);
        pb[ms] = pu.v;
      }
      const int voff = ((((2 * ns) + (qd >> 1)) ^ cx) << 3) + (qd & 1) * 4;
#pragma unroll
      for (int n8 = 0; n8 < 8; ++n8) {
        s16x4 vf = *(const s16x4*)&Vsl[(n8 * 16 + c) * 64 + voff];
        o[0][n8] = MFMA16(vf, pb[0], o[0][n8]);
        o[1][n8] = MFMA16(vf, pb[1], o[1][n8]);
      }
    }
#else
    unsigned pk[2][4][2];
#pragma unroll
    for (int ms = 0; ms < 2; ++ms)
#pragma unroll
      for (int ns = 0; ns < 4; ++ns) {
        pk[ms][ns][0] = pkbf(s[ms][ns][0], s[ms][ns][1]);
        pk[ms][ns][1] = pkbf(s[ms][ns][2], s[ms][ns][3]);
      }
    const bool hi = lane >= 32;
    const int sl0 = ((lane >> 4) & 1) * 32 + c;
    const int sl1 = sl0 + 16;
#pragma unroll
    for (int t2 = 0; t2 < 2; ++t2) {
      union { int i[4]; bf16x8 v; } pb[2];
#pragma unroll
      for (int ms = 0; ms < 2; ++ms)
#pragma unroll
        for (int dw = 0; dw < 4; ++dw) {
          int rg = dw & 1;
          int sl = dw < 2 ? sl0 : sl1;
          int va = __shfl((int)pk[ms][2 * t2][rg], sl, 64);
          int vb = __shfl((int)pk[ms][2 * t2 + 1][rg], sl, 64);
          pb[ms].i[dw] = hi ? vb : va;
        }
#pragma unroll
      for (int n8 = 0; n8 < 8; ++n8) {
        bf16x8 vf = *(const bf16x8*)
            &Vsl[(n8 * 16 + c) * 64 + (((4 * t2 + qd) ^ cx) << 3)];
        o[0][n8] = __builtin_amdgcn_mfma_f32_16x16x32_bf16(vf, pb[0].v, o[0][n8], 0, 0, 0);
        o[1][n8] = __builtin_amdgcn_mfma_f32_16x16x32_bf16(vf, pb[1].v, o[1][n8], 0, 0, 0);
      }
    }
#endif
  }
#pragma unroll
  for (int ms = 0; ms < 2; ++ms) {
    lrun[ms] += __shfl_xor(lrun[ms], 16, 64);
    lrun[ms] += __shfl_xor(lrun[ms], 32, 64);
  }
  if (qd == 0) {
    Lb[(qb + c) * 32 + h] = lrun[0];
    Lb[(qb + 16 + c) * 32 + h] = lrun[1];
  }
#pragma unroll
  for (int ms = 0; ms < 2; ++ms)
#pragma unroll
    for (int n8 = 0; n8 < 8; ++n8) {
      union { unsigned u[2]; s16x4 v; } w;
      w.u[0] = pkbf(o[ms][n8][0], o[ms][n8][1]);
      w.u[1] = pkbf(o[ms][n8][2], o[ms][n8][3]);
      *(s16x4*)&Ob[(size_t)(qb + ms * 16 + c) * 4096 + h * 128 + n8 * 16 + qd * 4] = w.v;
    }
}

// ---------------------------------------------------------------------------
// combine: O0 <- (O0 + O1) / (L0 + L1), elementwise over [2048][32][128].
// ---------------------------------------------------------------------------
__global__ __launch_bounds__(256) void combine(u16* __restrict__ O0,
                                               const u16* __restrict__ O1,
                                               const float* __restrict__ L0,
                                               const float* __restrict__ L1) {
  int i8 = (blockIdx.x * 256 + threadIdx.x) * 8;
  int q = i8 >> 12, h = (i8 >> 7) & 31;
  float inv = 1.0f / (L0[q * 32 + h] + L1[q * 32 + h]);
  bf16x8 a = *(bf16x8*)&O0[i8];
  bf16x8 b = *(const bf16x8*)&O1[i8];
  union { unsigned u[4]; bf16x8 v; } w;
#pragma unroll
  for (int j = 0; j < 4; ++j) {
    float e0 = (bf2f((u16)a[2 * j]) + bf2f((u16)b[2 * j])) * inv;
    float e1 = (bf2f((u16)a[2 * j + 1]) + bf2f((u16)b[2 * j + 1])) * inv;
    w.u[j] = pkbf(e0, e1);
  }
  *(bf16x8*)&O0[i8] = w.v;
}

// ---------------------------------------------------------------------------
extern "C" void kernel_launch(void* const* d_in, const int* in_sizes, int n_in,
                              void* d_out, int out_size, void* d_ws, size_t ws_size,
                              hipStream_t stream) {
  const float* x    = (const float*)d_in[0];
  const float* Wq   = (const float*)d_in[1];
  const float* Wk   = (const float*)d_in[2];
  const float* Wv   = (const float*)d_in[3];
  const float* Wo   = (const float*)d_in[4];
  const float* qnw  = (const float*)d_in[5];
  const float* knw  = (const float*)d_in[6];
  const float* sinb = (const float*)d_in[7];
  const float* cosb = (const float*)d_in[8];
  float* out = (float*)d_out;
  char* ws = (char*)d_ws;
  const size_t MB = 1024 * 1024;
  u16* WqkvT = (u16*)(ws + 0 * MB);
  u16* Op0   = (u16*)(ws + 0 * MB);
  float* L0f = (float*)(ws + 16 * MB);
  float* L1f = (float*)(ws + 16 * MB + 262144);
  u16* QKV = (u16*)(ws + 24 * MB);
  u16* WoT = (u16*)(ws + 24 * MB);
  u16* xb  = (u16*)(ws + 48 * MB);
  u16* Op1 = (u16*)(ws + 48 * MB);
  u16* VTb = (u16*)(ws + 64 * MB);

  prep<<<5120, 256, 0, stream>>>(x, xb, Wq, WqkvT,
                                 Wk, WqkvT + (size_t)4096 * 2048,
                                 Wv, WqkvT + (size_t)5120 * 2048);
  gemm_bt<<<dim3(48, 16), 256, 0, stream>>>(xb, WqkvT, QKV, 2048, 6144, 2048);
  norm_vt<<<2560, 256, 0, stream>>>(QKV, VTb, qnw, knw, sinb, cosb);
  flash<<<dim3(16, 32, 2), 256, 0, stream>>>(QKV, VTb, Op0, Op1, L0f, L1f);
  transpose_cast<<<dim3(32, 64), 256, 0, stream>>>(Wo, WoT, 2048, 4096);
  combine<<<4096, 256, 0, stream>>>(Op0, Op1, L0f, L1f);
  hipMemsetAsync(out, 0, (size_t)2048 * 2048 * 4, stream);
  gemm_bt_sk<<<dim3(16, 16, 2), 256, 0, stream>>>(Op0, WoT, out, 2048, 2048, 4096, 2048);
  (void)in_sizes; (void)n_in; (void)out_size; (void)ws_size;
}